// Round 6
// baseline (1264.330 us; speedup 1.0000x reference)
//
#include <hip/hip_runtime.h>
#include <math.h>

#define NN 25000
#define KNB 16
#define HH 128
#define VV 32000
#define BB 50
#define LL 128
#define NTK 4
#define NGRAPH 25
#define GCH 20

typedef __attribute__((ext_vector_type(8))) short s16x8;
typedef __attribute__((ext_vector_type(4))) float f32x4;
typedef _Float16 h16x2 __attribute__((ext_vector_type(2)));

__device__ __forceinline__ float fexp2(float x) {
#if __has_builtin(__builtin_amdgcn_exp2f)
    return __builtin_amdgcn_exp2f(x);
#else
    return exp2f(x);
#endif
}
__device__ __forceinline__ float frcp(float x) {
#if __has_builtin(__builtin_amdgcn_rcpf)
    return __builtin_amdgcn_rcpf(x);
#else
    return 1.f / x;
#endif
}
__device__ __forceinline__ float fsigm(float x) { return frcp(1.f + fexp2(x * -1.4426950408889634f)); }
__device__ __forceinline__ float ftanh(float x) { return 1.f - 2.f * frcp(1.f + fexp2(x * 2.8853900817779268f)); }

__device__ __forceinline__ unsigned short f2bf(float x) {
    unsigned int u = __float_as_uint(x);
    unsigned int r = (u + 0x7fffu + ((u >> 16) & 1u)) >> 16;
    return (unsigned short)r;
}
__device__ __forceinline__ float bf2f(unsigned int b) {
    return __uint_as_float((b & 0xffffu) << 16);
}

// broadcast value from lane (quadbase+Q) to all 4 lanes of each quad (gate redistribute)
template<int Q>
__device__ __forceinline__ float qb(float x) {
#if __has_builtin(__builtin_amdgcn_mov_dpp)
    return __int_as_float(__builtin_amdgcn_mov_dpp(__float_as_int(x), Q * 0x55, 0xf, 0xf, true));
#else
    return __shfl(x, (threadIdx.x & ~3) | Q, 64);
#endif
}

// packed f16 dot2
__device__ __forceinline__ float hdot(unsigned int a, unsigned int b, float c) {
#if __has_builtin(__builtin_amdgcn_fdot2)
    return __builtin_amdgcn_fdot2(__builtin_bit_cast(h16x2, a), __builtin_bit_cast(h16x2, b), c, false);
#else
    h16x2 av = __builtin_bit_cast(h16x2, a), bv = __builtin_bit_cast(h16x2, b);
    return c + (float)av[0] * (float)bv[0] + (float)av[1] * (float)bv[1];
#endif
}

// ---------------- embed f32 -> bf16 ----------------
__global__ __launch_bounds__(256) void embconv_k(const float* __restrict__ e,
                                                 unsigned short* __restrict__ o)
{
    int i = blockIdx.x * 256 + threadIdx.x;
    if (i < VV * 128) o[i] = f2bf(e[i]);
}

// ---------------- node bias gate-interleave (f32) ----------------
__global__ __launch_bounds__(512) void ndbperm_k(const float* __restrict__ ndb, float* __restrict__ out)
{
    int i = threadIdx.x;
    int unit = i >> 2, gate = i & 3;
    out[i] = ndb[gate * 128 + unit];
}

// ---------------- weight prep (unchanged layout from R5) ----------------
__global__ __launch_bounds__(256) void wprep_k(
    const float* __restrict__ ndWih, const float* __restrict__ ndWhh,
    const float* __restrict__ fWg0, const float* __restrict__ fWgr,
    const float* __restrict__ fWo0, const float* __restrict__ fWor,
    const float* __restrict__ bWg0, const float* __restrict__ bWgr,
    const float* __restrict__ bWo0, const float* __restrict__ bWor,
    const float* __restrict__ sfWih, const float* __restrict__ sbWih,
    const float* __restrict__ sfWhh, const float* __restrict__ sbWhh,
    unsigned short* __restrict__ dst)
{
    int idx = blockIdx.x * 256 + threadIdx.x;
    if (idx >= 1146880) return;
    if (idx >= 884736) {
        int r = idx - 884736;
        int d = r >> 17;
        int o = r & 131071;
        int pairIdx = o >> 1, hf = o & 1;
        int k2 = pairIdx >> 9, n = pairIdx & 511;
        int k = k2 * 2 + hf;
        int unit = n >> 2, gate = n & 3;
        const float* W = d ? sbWhh : sfWhh;
        _Float16 hv = (_Float16)W[(gate * 128 + unit) * 128 + k];
        dst[idx] = __builtin_bit_cast(unsigned short, hv);
        return;
    }
    float val;
    if (idx < 131072) {
        int r = idx >> 8, k = idx & 255;
        int unit = r >> 2, gate = r & 3;
        int srow = (gate << 7) + unit;
        val = (k < 128) ? ndWih[srow * 128 + k] : ndWhh[srow * 128 + (k - 128)];
    } else if (idx < 753664) {
        int r = idx - 131072;
        int dir = r / 311296;
        int o = r % 311296;
        const float* Wg0 = dir ? bWg0 : fWg0;
        const float* Wgr = dir ? bWgr : fWgr;
        const float* Wo0 = dir ? bWo0 : fWo0;
        const float* Wor = dir ? bWor : fWor;
        if (o < 16384) {
            int n = o >> 7, k = o & 127;
            val = Wg0[k * 128 + n];
        } else if (o < 147456) {
            int p = o - 16384;
            int j = p >> 16, q = p & 65535;
            int n = q >> 8, k = q & 255;
            val = Wgr[j * 65536 + k * 256 + n];
        } else if (o < 180224) {
            int p = o - 147456;
            int s = p >> 14, q = p & 16383;
            int n = q >> 7, k = q & 127;
            val = Wo0[s * 16384 + k * 128 + n];
        } else {
            int p = o - 180224;
            int js = p >> 15, q = p & 32767;
            int n = q >> 8, k = q & 255;
            val = Wor[js * 32768 + k * 128 + n];
        }
    } else if (idx < 819200) {
        val = sfWih[idx - 753664];
    } else {
        val = sbWih[idx - 819200];
    }
    dst[idx] = f2bf(val);
}

__global__ __launch_bounds__(256) void tokrev_k(const int* __restrict__ idx,
                                                const int* __restrict__ lens,
                                                int* __restrict__ tokrev)
{
    int t = blockIdx.x * 256 + threadIdx.x;
    if (t >= BB * LL) return;
    int b = t / LL, tt = t % LL;
    int r = lens[b] - 1 - tt;
    r = r < 0 ? 0 : (r > LL - 1 ? LL - 1 : r);
    tokrev[t] = idx[b * LL + r];
}

// ---------------- bf16 MFMA GEMM ----------------
// AMODE 0: A[m*lda+k]; 1: embed_bf[gidx[m*gs+go]*128+k]; 2: k<128 embed else H2[m*128+k-128]
// EP 0: none; 1: relu; 2: sigmoid(v)*aux_bf16[m*ldaux+n]
// OF32 1: out f32, 0: out bf16 ; PERM 1: permute out col n -> unit*4+gate
template<int AMODE, int EP, int OF32, int PERM>
__global__ __launch_bounds__(256) void hgemm_k(
    const unsigned short* __restrict__ A, int lda,
    const int* __restrict__ gidx, int gstride, int goff,
    const unsigned short* __restrict__ H2,
    const unsigned short* __restrict__ Wt, int ldw,   // [N][ldw] bf16
    const float* __restrict__ bias,
    const unsigned short* __restrict__ aux, int ldaux,
    void* __restrict__ outp, int ldo, int ocol,
    int M, int N, int K)
{
    __shared__ unsigned short Asm[128 * 64];
    __shared__ unsigned short Bsm[128 * 64];
    const int tid = threadIdx.x;
    const int lane = tid & 63, w = tid >> 6;
    const int wm = w >> 1, wn = w & 1;
    const int bm0 = blockIdx.x * 128, bn0 = blockIdx.y * 128;
    f32x4 acc[4][4];
#pragma unroll
    for (int i = 0; i < 4; ++i)
#pragma unroll
        for (int j = 0; j < 4; ++j) acc[i][j] = (f32x4){0.f, 0.f, 0.f, 0.f};

    for (int kt = 0; kt < K; kt += 64) {
#pragma unroll
        for (int r = 0; r < 4; ++r) {
            int id = tid + r * 256;
            int row = id >> 3, cc = id & 7;
            int m = bm0 + row;
            s16x8 v = {0, 0, 0, 0, 0, 0, 0, 0};
            if (m < M) {
                const unsigned short* src;
                if (AMODE == 0) {
                    src = A + (size_t)m * lda + kt + cc * 8;
                } else if (AMODE == 1) {
                    int g = gidx[m * gstride + goff];
                    src = A + (size_t)g * 128 + kt + cc * 8;
                } else {
                    int k0 = kt + cc * 8;
                    if (k0 < 128) {
                        int g = gidx[m * gstride + goff];
                        src = A + (size_t)g * 128 + k0;
                    } else {
                        src = H2 + (size_t)m * 128 + (k0 - 128);
                    }
                }
                v = *(const s16x8*)src;
            }
            int byt = (cc * 16) ^ ((row & 7) << 4);
            *(s16x8*)((char*)Asm + row * 128 + byt) = v;
        }
#pragma unroll
        for (int r = 0; r < 4; ++r) {
            int id = tid + r * 256;
            int row = id >> 3, cc = id & 7;
            s16x8 v = *(const s16x8*)(Wt + (size_t)(bn0 + row) * ldw + kt + cc * 8);
            int byt = (cc * 16) ^ ((row & 7) << 4);
            *(s16x8*)((char*)Bsm + row * 128 + byt) = v;
        }
        __syncthreads();
#pragma unroll
        for (int ks = 0; ks < 2; ++ks) {
            s16x8 af[4], bf[4];
#pragma unroll
            for (int mi = 0; mi < 4; ++mi) {
                int row = wm * 64 + mi * 16 + (lane & 15);
                int byt = (ks * 64 + ((lane >> 4) * 16)) ^ ((row & 7) << 4);
                af[mi] = *(const s16x8*)((char*)Asm + row * 128 + byt);
            }
#pragma unroll
            for (int ni = 0; ni < 4; ++ni) {
                int row = wn * 64 + ni * 16 + (lane & 15);
                int byt = (ks * 64 + ((lane >> 4) * 16)) ^ ((row & 7) << 4);
                bf[ni] = *(const s16x8*)((char*)Bsm + row * 128 + byt);
            }
#pragma unroll
            for (int mi = 0; mi < 4; ++mi)
#pragma unroll
                for (int ni = 0; ni < 4; ++ni)
                    acc[mi][ni] = __builtin_amdgcn_mfma_f32_16x16x32_bf16(af[mi], bf[ni], acc[mi][ni], 0, 0, 0);
        }
        __syncthreads();
    }
#pragma unroll
    for (int mi = 0; mi < 4; ++mi) {
#pragma unroll
        for (int ni = 0; ni < 4; ++ni) {
            int n = bn0 + wn * 64 + ni * 16 + (lane & 15);
#pragma unroll
            for (int j = 0; j < 4; ++j) {
                int m = bm0 + wm * 64 + mi * 16 + (lane >> 4) * 4 + j;
                if (m < M) {
                    float v = acc[mi][ni][j] + bias[n];
                    if (EP == 1) v = fmaxf(v, 0.f);
                    if (EP == 2) v = fsigm(v) * bf2f(aux[(size_t)m * ldaux + n]);
                    int nn = PERM ? (((n & 127) << 2) | (n >> 7)) : n;
                    if (OF32) ((float*)outp)[(size_t)m * ldo + ocol + nn] = v;
                    else ((unsigned short*)outp)[(size_t)m * ldo + ocol + nn] = f2bf(v);
                }
            }
        }
    }
}

// ---------------- persistent node LSTM: 64 nodes/block, 4 steps, c in regs, h in LDS ----------------
__global__ __launch_bounds__(256, 1) void node_lstm_k(
    const unsigned short* __restrict__ xg4,   // [100000][512] bf16, gate-interleaved cols, bias incl.
    const unsigned short* __restrict__ nodeW, // [512][256] bf16, rows unit*4+gate, cols [Wih|Whh]
    unsigned short* __restrict__ hout)        // [25000+][128] bf16
{
    __shared__ unsigned short hls[2][64 * 128];   // XOR-swizzled [node][unit]
    const int tid = threadIdx.x;
    const int lane = tid & 63, w = tid >> 6;      // wave w owns gate-cols [w*128, w*128+128)
    const int lane15 = lane & 15, hi = lane >> 4, q = lane & 3;
    const int nb0 = blockIdx.x * 64;
#pragma unroll
    for (int i = 0; i < 4; ++i)
        *(uint4*)((char*)&hls[0][0] + tid * 64 + i * 16) = make_uint4(0, 0, 0, 0);
    __syncthreads();
    float c[4][8];
#pragma unroll
    for (int mi = 0; mi < 4; ++mi)
#pragma unroll
        for (int ni = 0; ni < 8; ++ni) c[mi][ni] = 0.f;
    int pb = 0;
    for (int t = 0; t < NTK; ++t) {
#pragma unroll
        for (int half = 0; half < 2; ++half) {
            f32x4 acc[4][4];
#pragma unroll
            for (int mi = 0; mi < 4; ++mi)
#pragma unroll
                for (int ni = 0; ni < 4; ++ni) acc[mi][ni] = (f32x4){0.f, 0.f, 0.f, 0.f};
#pragma unroll
            for (int ks = 0; ks < 4; ++ks) {
                s16x8 bfr[4], afr[4];
#pragma unroll
                for (int nih = 0; nih < 4; ++nih) {
                    int nrow = w * 128 + (half * 4 + nih) * 16 + lane15;
                    bfr[nih] = *(const s16x8*)(nodeW + (size_t)nrow * 256 + 128 + ks * 32 + hi * 8);
                }
#pragma unroll
                for (int mi = 0; mi < 4; ++mi) {
                    int m = mi * 16 + lane15;
                    int colb = (ks * 32 + hi * 8) * 2;
                    afr[mi] = *(const s16x8*)((const char*)&hls[pb][0] + m * 256 + (colb ^ ((m & 7) << 4)));
                }
#pragma unroll
                for (int mi = 0; mi < 4; ++mi)
#pragma unroll
                    for (int nih = 0; nih < 4; ++nih)
                        acc[mi][nih] = __builtin_amdgcn_mfma_f32_16x16x32_bf16(afr[mi], bfr[nih], acc[mi][nih], 0, 0, 0);
            }
            // epilogue: gates -> cell -> h(t+1)
#pragma unroll
            for (int mi = 0; mi < 4; ++mi) {
#pragma unroll
                for (int nih = 0; nih < 4; ++nih) {
                    int ni = half * 4 + nih;
                    int n = w * 128 + ni * 16 + lane15;
                    int unit = n >> 2;
#pragma unroll
                    for (int j = 0; j < 4; ++j) {
                        int m = mi * 16 + hi * 4 + j;
                        size_t grow = (size_t)((nb0 + m) * 4 + t);
                        float xv = bf2f(xg4[grow * 512 + n]);
                        float v = acc[mi][nih][j] + xv;
                        float tv = (q == 2) ? ftanh(v) : fsigm(v);
                        float gi = qb<0>(tv), gf = qb<1>(tv), gg = qb<2>(tv), go = qb<3>(tv);
                        if (q == j) {
                            float cc = gf * c[mi][ni] + gi * gg;
                            c[mi][ni] = cc;
                            float hv = go * ftanh(cc);
                            int cb2 = (unit * 2) ^ ((m & 7) << 4);
                            *(unsigned short*)((char*)&hls[pb ^ 1][0] + m * 256 + cb2) = f2bf(hv);
                        }
                    }
                }
            }
        }
        __syncthreads();
        pb ^= 1;
    }
    // copy out final h (deswizzle), coalesced
    {
        int node = tid >> 2, seg = tid & 3;
#pragma unroll
        for (int qq = 0; qq < 4; ++qq) {
            int cb = seg * 64 + qq * 16;
            uint4 v = *(const uint4*)((const char*)&hls[pb][0] + node * 256 + (cb ^ ((node & 7) << 4)));
            *(uint4*)((char*)(hout + (size_t)(nb0 + node) * 128) + cb) = v;
        }
    }
}

// ---------------- per-sequence LSTM recurrence (packed f16 dot2, gate-interleaved) ----------------
__global__ __launch_bounds__(512, 2) void seq_lstm_k(const float* __restrict__ xgf,
                                                     const float* __restrict__ xgb,
                                                     const unsigned short* __restrict__ wseq,
                                                     const int* __restrict__ lens,
                                                     float* __restrict__ senc)
{
    int bid = blockIdx.x;
    int dir = bid >= BB ? 1 : 0;
    int b = dir ? bid - BB : bid;
    int len = lens[b];
    const float* xg = (dir ? xgb : xgf) + (size_t)b * LL * 512;
    const unsigned int* wp = (const unsigned int*)(wseq + dir * 131072);
    int tid = threadIdx.x;
    int q = tid & 3, unit = tid >> 2;
    unsigned int wreg[64];
#pragma unroll
    for (int k2 = 0; k2 < 64; ++k2) wreg[k2] = wp[k2 * 512 + tid];
    __shared__ __align__(16) unsigned short hlsq[2][128];
    float cj = 0.f;
    if (tid < 128) hlsq[0][tid] = 0;
    __syncthreads();
    float xcur = xg[tid];
    int pb = 0;
    for (int t = 0; t < len; ++t) {
        float xnext = (t + 1 < len) ? xg[(size_t)(t + 1) * 512 + tid] : 0.f;
        const uint4* hp = (const uint4*)&hlsq[pb][0];
        float p0 = 0.f, p1 = 0.f, p2 = 0.f, p3 = 0.f;
#pragma unroll
        for (int i = 0; i < 4; ++i) {
            uint4 h0 = hp[i * 4 + 0], h1 = hp[i * 4 + 1], h2 = hp[i * 4 + 2], h3 = hp[i * 4 + 3];
            const unsigned int* w0 = &wreg[i * 16];
            p0 = hdot(h0.x, w0[0], p0);  p0 = hdot(h0.y, w0[1], p0);
            p0 = hdot(h0.z, w0[2], p0);  p0 = hdot(h0.w, w0[3], p0);
            p1 = hdot(h1.x, w0[4], p1);  p1 = hdot(h1.y, w0[5], p1);
            p1 = hdot(h1.z, w0[6], p1);  p1 = hdot(h1.w, w0[7], p1);
            p2 = hdot(h2.x, w0[8], p2);  p2 = hdot(h2.y, w0[9], p2);
            p2 = hdot(h2.z, w0[10], p2); p2 = hdot(h2.w, w0[11], p2);
            p3 = hdot(h3.x, w0[12], p3); p3 = hdot(h3.y, w0[13], p3);
            p3 = hdot(h3.z, w0[14], p3); p3 = hdot(h3.w, w0[15], p3);
        }
        float accv = xcur + ((p0 + p1) + (p2 + p3));
        float tv = (q == 2) ? ftanh(accv) : fsigm(accv);
        float v1 = __shfl_xor(tv, 1), v2 = __shfl_xor(tv, 2), v3 = __shfl_xor(tv, 3);
        if (q == 0) {
            cj = v1 * cj + tv * v2;
            float hv = v3 * ftanh(cj);
            _Float16 hh = (_Float16)hv;
            hlsq[pb ^ 1][unit] = __builtin_bit_cast(unsigned short, hh);
            int tout = dir ? (len - 1 - t) : t;
            senc[((size_t)b * LL + tout) * 256 + dir * 128 + unit] = hv;
        }
        __syncthreads();
        pb ^= 1;
        xcur = xnext;
    }
}

// ---------------- mask + zero-invalid + max_len ----------------
__global__ __launch_bounds__(256) void finalize_k(const int* __restrict__ idx,
                                                  const int* __restrict__ lens,
                                                  float* __restrict__ senc,
                                                  float* __restrict__ mask,
                                                  float* __restrict__ omax,
                                                  const int* __restrict__ mlin)
{
    int id = blockIdx.x * 256 + threadIdx.x;
    if (id == 0) omax[0] = (float)mlin[0];
    if (id >= BB * LL * 64) return;
    int row = id >> 6, c = id & 63;
    int b = row / LL, tt = row % LL;
    if (c == 0) mask[row] = (idx[row] == 0) ? 1.f : 0.f;
    if (tt >= lens[b]) *(float4*)&senc[(size_t)row * 256 + c * 4] = make_float4(0.f, 0.f, 0.f, 0.f);
}

// ---------------- gated-attention context (bf16 in, bf16 out) ----------------
template<int D>
__global__ __launch_bounds__(256) void attn_ctx_k(const unsigned short* __restrict__ hid,
                                                  const int* __restrict__ adj,
                                                  const float* __restrict__ att0,
                                                  const float* __restrict__ att1,
                                                  unsigned short* __restrict__ ctx)
{
    constexpr int V = D / 64;
    int lane = threadIdx.x & 63, wid = threadIdx.x >> 6;
    int n = blockIdx.x * 4 + wid;
    if (n >= NN) return;
    float a0[V], a1[V], sv[V];
#pragma unroll
    for (int j = 0; j < V; ++j) {
        a0[j] = att0[lane * V + j];
        a1[j] = att1[lane * V + j];
    }
    {
        if (V == 2) {
            unsigned int u = *(const unsigned int*)(hid + (size_t)n * D + lane * 2);
            sv[0] = bf2f(u); sv[1] = bf2f(u >> 16);
        } else {
            uint2 u = *(const uint2*)(hid + (size_t)n * D + lane * 4);
            sv[0] = bf2f(u.x); sv[1] = bf2f(u.x >> 16);
            sv[2] = bf2f(u.y); sv[3] = bf2f(u.y >> 16);
        }
    }
    float p = 0.f;
#pragma unroll
    for (int j = 0; j < V; ++j) p += sv[j] * a0[j];
#pragma unroll
    for (int m = 1; m < 64; m <<= 1) p += __shfl_xor(p, m);
    float s_self = p;
    float nv[KNB][V];
    float sc[KNB];
#pragma unroll
    for (int k = 0; k < KNB; ++k) {
        int nb = adj[n * KNB + k];
        float qv = 0.f;
        if (nb < NN) {
            if (V == 2) {
                unsigned int u = *(const unsigned int*)(hid + (size_t)nb * D + lane * 2);
                nv[k][0] = bf2f(u); nv[k][1] = bf2f(u >> 16);
            } else {
                uint2 u = *(const uint2*)(hid + (size_t)nb * D + lane * 4);
                nv[k][0] = bf2f(u.x); nv[k][1] = bf2f(u.x >> 16);
                nv[k][2] = bf2f(u.y); nv[k][3] = bf2f(u.y >> 16);
            }
        } else {
#pragma unroll
            for (int j = 0; j < V; ++j) nv[k][j] = 0.f;
        }
#pragma unroll
        for (int j = 0; j < V; ++j) qv += nv[k][j] * a1[j];
#pragma unroll
        for (int m = 1; m < 64; m <<= 1) qv += __shfl_xor(qv, m);
        sc[k] = s_self + qv;
    }
    float mx = sc[0];
#pragma unroll
    for (int k = 1; k < KNB; ++k) mx = fmaxf(mx, sc[k]);
    float s = 0.f;
#pragma unroll
    for (int k = 0; k < KNB; ++k) { sc[k] = fexp2((sc[k] - mx) * 1.4426950408889634f); s += sc[k]; }
    float inv = frcp(s);
#pragma unroll
    for (int j2 = 0; j2 < V; j2 += 2) {
        float c0 = 0.f, c1 = 0.f;
#pragma unroll
        for (int k = 0; k < KNB; ++k) { c0 += sc[k] * nv[k][j2]; c1 += sc[k] * nv[k][j2 + 1]; }
        unsigned int pk = (unsigned int)f2bf(c0 * inv) | ((unsigned int)f2bf(c1 * inv) << 16);
        *(unsigned int*)(ctx + (size_t)n * D + lane * V + j2) = pk;
    }
}

// ---------------- graph max pool: two-stage ----------------
__global__ __launch_bounds__(512) void gmax1_k(const float* __restrict__ gh, float* __restrict__ part)
{
    int g = blockIdx.x, ch = blockIdx.y;
    int c = threadIdx.x;
    const float* p = gh + ((size_t)g * 1000 + ch * (1000 / GCH)) * 512 + c;
    float m = -1e30f;
#pragma unroll 5
    for (int i = 0; i < 1000 / GCH; ++i) m = fmaxf(m, p[(size_t)i * 512]);
    part[((size_t)g * GCH + ch) * 512 + c] = m;
}

__global__ __launch_bounds__(512) void gmax2_k(const float* __restrict__ part, float* __restrict__ ge)
{
    int g = blockIdx.x;
    int c = threadIdx.x;
    float m = -1e30f;
#pragma unroll
    for (int i = 0; i < GCH; ++i) m = fmaxf(m, part[((size_t)g * GCH + i) * 512 + c]);
    ge[g * 512 + c] = m;
}

extern "C" void kernel_launch(void* const* d_in, const int* in_sizes, int n_in,
                              void* d_out, int out_size, void* d_ws, size_t ws_size,
                              hipStream_t stream)
{
    const float* embed = (const float*)d_in[0];
    const float* sfWhh = (const float*)d_in[2];
    const float* sfb   = (const float*)d_in[3];
    const float* sbWhh = (const float*)d_in[5];
    const float* sbb   = (const float*)d_in[6];
    const float* ndWih = (const float*)d_in[7];
    const float* ndWhh = (const float*)d_in[8];
    const float* ndb   = (const float*)d_in[9];
    const int* nodefeat = (const int*)d_in[30];
    const int* adjs[2]  = {(const int*)d_in[31], (const int*)d_in[32]};
    const int* idxseq   = (const int*)d_in[33];
    const int* lens     = (const int*)d_in[34];
    const int* mlin     = (const int*)d_in[35];

    // ---- workspace layout (f32 offsets), phase-aliased; peak 28,224,000 f32 = 112.9 MB ----
    float* ws = (float*)d_ws;
    unsigned short* embedbf = (unsigned short*)ws;                 // [0, 2,048,000) f32
    unsigned short* warena  = (unsigned short*)(ws + 2048000);     // [2,048,000, 2,621,440)
    float* ndbp  = ws + 2621440;                                   // 512 f32
    unsigned short* hbf = (unsigned short*)ws;                     // overlays embedbf (dead after xg4 GEMM)
    // phase 1 (dead after seq_lstm):
    float* xgf = ws + 2624000;                                     // 3,276,800
    float* xgb = ws + 5900800;                                     // 3,276,800
    int*   tokrev = (int*)(ws + 9177600);                          // 6,400
    // phase 2 (overlays phase 1):
    unsigned short* xg4 = (unsigned short*)(ws + 2624000);         // 51,200,000 us = 25.6M f32
    // phase 3 (overlays xg4):
    unsigned short* HA    = (unsigned short*)(ws + 2624000);       // 6.4M us
    unsigned short* HB    = (unsigned short*)(ws + 5824000);       // 6.4M us
    unsigned short* ctxb  = (unsigned short*)(ws + 9024000);       // 6.4M us
    unsigned short* gctxb = (unsigned short*)(ws + 12224000);      // 6.4M us
    float* gmaxp = ws + 2624000;                                   // phase 4 partials

    float* outf  = (float*)d_out;
    float* gh    = outf;                 // 12,800,000
    float* ge    = outf + 12800000;      // 12,800
    float* omax  = outf + 12812800;      // 1
    float* senc  = outf + 12812801;      // 1,638,400
    float* omask = outf + 14451201;      // 6,400

    // phase 0: preps
    tokrev_k<<<dim3((BB * LL + 255) / 256), dim3(256), 0, stream>>>(idxseq, lens, tokrev);
    embconv_k<<<dim3(VV * 128 / 256), dim3(256), 0, stream>>>(embed, embedbf);
    ndbperm_k<<<dim3(1), dim3(512), 0, stream>>>(ndb, ndbp);
    wprep_k<<<dim3(4480), dim3(256), 0, stream>>>(ndWih, ndWhh,
        (const float*)d_in[12], (const float*)d_in[14], (const float*)d_in[16], (const float*)d_in[18],
        (const float*)d_in[22], (const float*)d_in[24], (const float*)d_in[26], (const float*)d_in[28],
        (const float*)d_in[1], (const float*)d_in[4], sfWhh, sbWhh, warena);

    // phase 1: sequence bi-LSTM
    hgemm_k<1, 0, 1, 1><<<dim3(50, 4), dim3(256), 0, stream>>>(embedbf, 0, idxseq, 1, 0, nullptr,
        warena + 753664, 128, sfb, nullptr, 0, xgf, 512, 0, BB * LL, 512, 128);
    hgemm_k<1, 0, 1, 1><<<dim3(50, 4), dim3(256), 0, stream>>>(embedbf, 0, tokrev, 1, 0, nullptr,
        warena + 819200, 128, sbb, nullptr, 0, xgb, 512, 0, BB * LL, 512, 128);
    seq_lstm_k<<<dim3(2 * BB), dim3(512), 0, stream>>>(xgf, xgb, warena + 884736, lens, senc);
    finalize_k<<<dim3(1600), dim3(256), 0, stream>>>(idxseq, lens, senc, omask, omax, mlin);

    // phase 2: node LSTM — one big xg GEMM + persistent recurrence
    hgemm_k<1, 0, 0, 0><<<dim3(782, 4), dim3(256), 0, stream>>>(embedbf, 0, nodefeat, 1, 0, nullptr,
        warena, 256, ndbp, nullptr, 0, xg4, 512, 0, NN * NTK, 512, 128);
    node_lstm_k<<<dim3(391), dim3(256), 0, stream>>>(xg4, warena, hbf);

    // phase 3: graph attention layers
    for (int dir = 0; dir < 2; ++dir) {
        int base = 10 + dir * 10;
        const float* att0w = (const float*)d_in[base + 0];
        const float* attrw = (const float*)d_in[base + 1];
        const float* bg0   = (const float*)d_in[base + 3];
        const float* bgr   = (const float*)d_in[base + 5];
        const float* bo0   = (const float*)d_in[base + 7];
        const float* bor   = (const float*)d_in[base + 9];
        const int* adj = adjs[dir];
        const unsigned short* wb = warena + 131072 + dir * 311296;
        for (int l = 0; l < 3; ++l) {
            int D = (l == 0) ? 128 : 256;
            int j = l - 1;
            const unsigned short* cur = (l == 0) ? hbf : (l == 1 ? HA : HB);
            const float* a0 = (l == 0) ? att0w : attrw + (size_t)j * 512;
            const float* a1 = (l == 0) ? att0w + 128 : attrw + (size_t)j * 512 + 256;
            const unsigned short* wg  = (l == 0) ? wb : wb + 16384 + j * 65536;
            const unsigned short* wos = (l == 0) ? wb + 147456 : wb + 180224 + (j * 2 + 0) * 32768;
            const unsigned short* won = (l == 0) ? wb + 163840 : wb + 180224 + (j * 2 + 1) * 32768;
            const float* bg = (l == 0) ? bg0 : bgr + (size_t)j * 256;
            const float* bos = (l == 0) ? bo0 : bor + (size_t)j * 256;
            const float* bon = (l == 0) ? bo0 + 128 : bor + (size_t)j * 256 + 128;

            if (D == 128)
                attn_ctx_k<128><<<dim3(NN / 4), dim3(256), 0, stream>>>(cur, adj, a0, a1, ctxb);
            else
                attn_ctx_k<256><<<dim3(NN / 4), dim3(256), 0, stream>>>(cur, adj, a0, a1, ctxb);

            hgemm_k<0, 2, 0, 0><<<dim3(196, D / 128), dim3(256), 0, stream>>>(cur, D, nullptr, 0, 0, nullptr,
                wg, D, bg, ctxb, D, gctxb, D, 0, NN, D, D);

            if (l == 2) {
                hgemm_k<0, 1, 1, 0><<<dim3(196, 1), dim3(256), 0, stream>>>(cur, D, nullptr, 0, 0, nullptr,
                    wos, D, bos, nullptr, 0, gh, 512, dir * 256, NN, 128, D);
                hgemm_k<0, 1, 1, 0><<<dim3(196, 1), dim3(256), 0, stream>>>(gctxb, D, nullptr, 0, 0, nullptr,
                    won, D, bon, nullptr, 0, gh, 512, dir * 256 + 128, NN, 128, D);
            } else {
                unsigned short* ob = (l == 0) ? HA : HB;
                hgemm_k<0, 1, 0, 0><<<dim3(196, 1), dim3(256), 0, stream>>>(cur, D, nullptr, 0, 0, nullptr,
                    wos, D, bos, nullptr, 0, ob, 256, 0, NN, 128, D);
                hgemm_k<0, 1, 0, 0><<<dim3(196, 1), dim3(256), 0, stream>>>(gctxb, D, nullptr, 0, 0, nullptr,
                    won, D, bon, nullptr, 0, ob, 256, 128, NN, 128, D);
            }
        }
    }

    // phase 4: graph embedding max-pool (two-stage)
    gmax1_k<<<dim3(NGRAPH, GCH), dim3(512), 0, stream>>>(gh, gmaxp);
    gmax2_k<<<dim3(NGRAPH), dim3(512), 0, stream>>>(gmaxp, ge);
}

// Round 7
// 1014.109 us; speedup vs baseline: 1.2467x; 1.2467x over previous
//
#include <hip/hip_runtime.h>
#include <math.h>

#define NN 25000
#define KNB 16
#define HH 128
#define VV 32000
#define BB 50
#define LL 128
#define NTK 4
#define NGRAPH 25
#define GCH 20

typedef __attribute__((ext_vector_type(8))) short s16x8;
typedef __attribute__((ext_vector_type(4))) float f32x4;
typedef _Float16 h16x2 __attribute__((ext_vector_type(2)));

__device__ __forceinline__ float fexp2(float x) {
#if __has_builtin(__builtin_amdgcn_exp2f)
    return __builtin_amdgcn_exp2f(x);
#else
    return exp2f(x);
#endif
}
__device__ __forceinline__ float frcp(float x) {
#if __has_builtin(__builtin_amdgcn_rcpf)
    return __builtin_amdgcn_rcpf(x);
#else
    return 1.f / x;
#endif
}
__device__ __forceinline__ float fsigm(float x) { return frcp(1.f + fexp2(x * -1.4426950408889634f)); }
__device__ __forceinline__ float ftanh(float x) { return 1.f - 2.f * frcp(1.f + fexp2(x * 2.8853900817779268f)); }

__device__ __forceinline__ unsigned short f2bf(float x) {
    unsigned int u = __float_as_uint(x);
    unsigned int r = (u + 0x7fffu + ((u >> 16) & 1u)) >> 16;
    return (unsigned short)r;
}
__device__ __forceinline__ float bf2f(unsigned int b) {
    return __uint_as_float((b & 0xffffu) << 16);
}

// packed f16 dot2
__device__ __forceinline__ float hdot(unsigned int a, unsigned int b, float c) {
#if __has_builtin(__builtin_amdgcn_fdot2)
    return __builtin_amdgcn_fdot2(__builtin_bit_cast(h16x2, a), __builtin_bit_cast(h16x2, b), c, false);
#else
    h16x2 av = __builtin_bit_cast(h16x2, a), bv = __builtin_bit_cast(h16x2, b);
    return c + (float)av[0] * (float)bv[0] + (float)av[1] * (float)bv[1];
#endif
}

__global__ __launch_bounds__(256) void zero_k(float* __restrict__ p, int n)
{
    int i = blockIdx.x * 256 + threadIdx.x;
    if (i < n) p[i] = 0.f;
}

// ---------------- embed f32 -> bf16 ----------------
__global__ __launch_bounds__(256) void embconv_k(const float* __restrict__ e,
                                                 unsigned short* __restrict__ o)
{
    int i = blockIdx.x * 256 + threadIdx.x;
    if (i < VV * 128) o[i] = f2bf(e[i]);
}

// ---------------- weight prep (same arena layout as R5) ----------------
__global__ __launch_bounds__(256) void wprep_k(
    const float* __restrict__ ndWih, const float* __restrict__ ndWhh,
    const float* __restrict__ fWg0, const float* __restrict__ fWgr,
    const float* __restrict__ fWo0, const float* __restrict__ fWor,
    const float* __restrict__ bWg0, const float* __restrict__ bWgr,
    const float* __restrict__ bWo0, const float* __restrict__ bWor,
    const float* __restrict__ sfWih, const float* __restrict__ sbWih,
    const float* __restrict__ sfWhh, const float* __restrict__ sbWhh,
    unsigned short* __restrict__ dst)
{
    int idx = blockIdx.x * 256 + threadIdx.x;
    if (idx >= 1146880) return;
    if (idx >= 884736) {
        int r = idx - 884736;
        int d = r >> 17;
        int o = r & 131071;
        int pairIdx = o >> 1, hf = o & 1;
        int k2 = pairIdx >> 9, n = pairIdx & 511;
        int k = k2 * 2 + hf;
        int unit = n >> 2, gate = n & 3;
        const float* W = d ? sbWhh : sfWhh;
        _Float16 hv = (_Float16)W[(gate * 128 + unit) * 128 + k];
        dst[idx] = __builtin_bit_cast(unsigned short, hv);
        return;
    }
    float val;
    if (idx < 131072) {
        int r = idx >> 8, k = idx & 255;
        int unit = r >> 2, gate = r & 3;
        int srow = (gate << 7) + unit;
        val = (k < 128) ? ndWih[srow * 128 + k] : ndWhh[srow * 128 + (k - 128)];
    } else if (idx < 753664) {
        int r = idx - 131072;
        int dir = r / 311296;
        int o = r % 311296;
        const float* Wg0 = dir ? bWg0 : fWg0;
        const float* Wgr = dir ? bWgr : fWgr;
        const float* Wo0 = dir ? bWo0 : fWo0;
        const float* Wor = dir ? bWor : fWor;
        if (o < 16384) {
            int n = o >> 7, k = o & 127;
            val = Wg0[k * 128 + n];
        } else if (o < 147456) {
            int p = o - 16384;
            int j = p >> 16, q = p & 65535;
            int n = q >> 8, k = q & 255;
            val = Wgr[j * 65536 + k * 256 + n];
        } else if (o < 180224) {
            int p = o - 147456;
            int s = p >> 14, q = p & 16383;
            int n = q >> 7, k = q & 127;
            val = Wo0[s * 16384 + k * 128 + n];
        } else {
            int p = o - 180224;
            int js = p >> 15, q = p & 32767;
            int n = q >> 8, k = q & 255;
            val = Wor[js * 32768 + k * 128 + n];
        }
    } else if (idx < 819200) {
        val = sfWih[idx - 753664];
    } else {
        val = sbWih[idx - 819200];
    }
    dst[idx] = f2bf(val);
}

__global__ __launch_bounds__(256) void tokrev_k(const int* __restrict__ idx,
                                                const int* __restrict__ lens,
                                                int* __restrict__ tokrev)
{
    int t = blockIdx.x * 256 + threadIdx.x;
    if (t >= BB * LL) return;
    int b = t / LL, tt = t % LL;
    int r = lens[b] - 1 - tt;
    r = r < 0 ? 0 : (r > LL - 1 ? LL - 1 : r);
    tokrev[t] = idx[b * LL + r];
}

// ---------------- bf16 MFMA GEMM (R5 version, for phase 1 + node phase) ----------------
// AMODE 1: embed_bf[gidx[m*gs+go]*128+k]; 2: k<128 embed else H2[m*128+k-128]
// EP 0: none; 3: fused LSTM cell (gate-interleaved N)
// OF32 1: out f32 ; PERM 1: permute out col n -> unit*4+gate
template<int AMODE, int EP, int OF32, int PERM>
__global__ __launch_bounds__(256) void hgemm_k(
    const unsigned short* __restrict__ A, int lda,
    const int* __restrict__ gidx, int gstride, int goff,
    const unsigned short* __restrict__ H2,
    const unsigned short* __restrict__ Wt,   // [N][K] bf16
    const float* __restrict__ bias,
    void* __restrict__ outp, int ldo, int ocol,
    int M, int N, int K, float* __restrict__ cbuf)
{
    __shared__ unsigned short Asm[128 * 64];
    __shared__ unsigned short Bsm[128 * 64];
    const int tid = threadIdx.x;
    const int lane = tid & 63, w = tid >> 6;
    const int wm = w >> 1, wn = w & 1;
    const int bm0 = blockIdx.x * 128, bn0 = blockIdx.y * 128;
    f32x4 acc[4][4];
#pragma unroll
    for (int i = 0; i < 4; ++i)
#pragma unroll
        for (int j = 0; j < 4; ++j) acc[i][j] = (f32x4){0.f, 0.f, 0.f, 0.f};

    for (int kt = 0; kt < K; kt += 64) {
#pragma unroll
        for (int r = 0; r < 4; ++r) {
            int id = tid + r * 256;
            int row = id >> 3, cc = id & 7;
            int m = bm0 + row;
            s16x8 v = {0, 0, 0, 0, 0, 0, 0, 0};
            if (m < M) {
                const unsigned short* src;
                if (AMODE == 1) {
                    int g = gidx[m * gstride + goff];
                    src = A + (size_t)g * 128 + kt + cc * 8;
                } else {
                    int k0 = kt + cc * 8;
                    if (k0 < 128) {
                        int g = gidx[m * gstride + goff];
                        src = A + (size_t)g * 128 + k0;
                    } else {
                        src = H2 + (size_t)m * 128 + (k0 - 128);
                    }
                }
                v = *(const s16x8*)src;
            }
            int byt = (cc * 16) ^ ((row & 7) << 4);
            *(s16x8*)((char*)Asm + row * 128 + byt) = v;
        }
#pragma unroll
        for (int r = 0; r < 4; ++r) {
            int id = tid + r * 256;
            int row = id >> 3, cc = id & 7;
            s16x8 v = *(const s16x8*)(Wt + (size_t)(bn0 + row) * K + kt + cc * 8);
            int byt = (cc * 16) ^ ((row & 7) << 4);
            *(s16x8*)((char*)Bsm + row * 128 + byt) = v;
        }
        __syncthreads();
#pragma unroll
        for (int ks = 0; ks < 2; ++ks) {
            s16x8 af[4], bf[4];
#pragma unroll
            for (int mi = 0; mi < 4; ++mi) {
                int row = wm * 64 + mi * 16 + (lane & 15);
                int byt = (ks * 64 + ((lane >> 4) * 16)) ^ ((row & 7) << 4);
                af[mi] = *(const s16x8*)((char*)Asm + row * 128 + byt);
            }
#pragma unroll
            for (int ni = 0; ni < 4; ++ni) {
                int row = wn * 64 + ni * 16 + (lane & 15);
                int byt = (ks * 64 + ((lane >> 4) * 16)) ^ ((row & 7) << 4);
                bf[ni] = *(const s16x8*)((char*)Bsm + row * 128 + byt);
            }
#pragma unroll
            for (int mi = 0; mi < 4; ++mi)
#pragma unroll
                for (int ni = 0; ni < 4; ++ni)
                    acc[mi][ni] = __builtin_amdgcn_mfma_f32_16x16x32_bf16(af[mi], bf[ni], acc[mi][ni], 0, 0, 0);
        }
        __syncthreads();
    }
    if (EP == 3) {
#pragma unroll
        for (int mi = 0; mi < 4; ++mi) {
#pragma unroll
            for (int ni = 0; ni < 4; ++ni) {
                int n = bn0 + wn * 64 + ni * 16 + (lane & 15);
                int unit = n >> 2, gate = n & 3;
                float bval = bias[(gate << 7) + unit];
#pragma unroll
                for (int j = 0; j < 4; ++j) {
                    int m = bm0 + wm * 64 + mi * 16 + (lane >> 4) * 4 + j;
                    float v = acc[mi][ni][j] + bval;
                    float tv = (gate == 2) ? ftanh(v) : fsigm(v);
                    float v1 = __shfl_xor(tv, 1), v2 = __shfl_xor(tv, 2), v3 = __shfl_xor(tv, 3);
                    if (gate == 0 && m < M) {
                        float cc = cbuf[(size_t)m * HH + unit];
                        cc = v1 * cc + tv * v2;
                        cbuf[(size_t)m * HH + unit] = cc;
                        ((unsigned short*)outp)[(size_t)m * HH + unit] = f2bf(v3 * ftanh(cc));
                    }
                }
            }
        }
    } else {
#pragma unroll
        for (int mi = 0; mi < 4; ++mi) {
#pragma unroll
            for (int ni = 0; ni < 4; ++ni) {
                int n = bn0 + wn * 64 + ni * 16 + (lane & 15);
#pragma unroll
                for (int j = 0; j < 4; ++j) {
                    int m = bm0 + wm * 64 + mi * 16 + (lane >> 4) * 4 + j;
                    if (m < M) {
                        float v = acc[mi][ni][j] + bias[n];
                        int nn = PERM ? (((n & 127) << 2) | (n >> 7)) : n;
                        if (OF32) ((float*)outp)[(size_t)m * ldo + ocol + nn] = v;
                        else ((unsigned short*)outp)[(size_t)m * ldo + ocol + nn] = f2bf(v);
                    }
                }
            }
        }
    }
}

// ---------------- phase-3 batched GEMM: dirs via grid.z, roles/N-tiles via grid.y ----------------
// mode 0: gate  — EP sigmoid(v)*aux (in-place ctx), bf16 out; grid.y = N-tile of D
// mode 1: out   — relu, bf16 out; grid.y = role (0: A0=cur/W panel 0, 1: A1=gctx/W panel 1)
// mode 2: out   — relu, f32 out (final layer -> gh)
__global__ __launch_bounds__(256) void hgemm3_k(
    const unsigned short* __restrict__ A0, int a0ds,
    const unsigned short* __restrict__ A1, int a1ds,
    const unsigned short* __restrict__ Wb, int wds, int wrs,
    const float* __restrict__ b0, const float* __restrict__ b1,
    const unsigned short* __restrict__ auxb, int auxds,
    void* __restrict__ outb, int outds, int ldo, int ocolDS,
    int M, int K, int D, int mode)
{
    __shared__ unsigned short Asm[128 * 64];
    __shared__ unsigned short Bsm[128 * 64];
    const int tid = threadIdx.x;
    const int lane = tid & 63, w = tid >> 6;
    const int wm = w >> 1, wn = w & 1;
    const int bm0 = blockIdx.x * 128;
    const int dir = blockIdx.z, y = blockIdx.y;
    const int colBase = y * 128;
    const unsigned short* A = (mode == 0 || y == 0) ? (A0 + (size_t)dir * a0ds)
                                                    : (A1 + (size_t)dir * a1ds);
    const unsigned short* Wt = Wb + (size_t)dir * wds
                             + ((mode == 0) ? (size_t)colBase * K : (size_t)y * wrs);
    const float* bias = (dir ? b1 : b0) + colBase;
    const unsigned short* aux = auxb ? (auxb + (size_t)dir * auxds) : nullptr;

    f32x4 acc[4][4];
#pragma unroll
    for (int i = 0; i < 4; ++i)
#pragma unroll
        for (int j = 0; j < 4; ++j) acc[i][j] = (f32x4){0.f, 0.f, 0.f, 0.f};

    for (int kt = 0; kt < K; kt += 64) {
#pragma unroll
        for (int r = 0; r < 4; ++r) {
            int id = tid + r * 256;
            int row = id >> 3, cc = id & 7;
            int m = bm0 + row;
            s16x8 v = {0, 0, 0, 0, 0, 0, 0, 0};
            if (m < M) v = *(const s16x8*)(A + (size_t)m * K + kt + cc * 8);
            int byt = (cc * 16) ^ ((row & 7) << 4);
            *(s16x8*)((char*)Asm + row * 128 + byt) = v;
        }
#pragma unroll
        for (int r = 0; r < 4; ++r) {
            int id = tid + r * 256;
            int row = id >> 3, cc = id & 7;
            s16x8 v = *(const s16x8*)(Wt + (size_t)row * K + kt + cc * 8);
            int byt = (cc * 16) ^ ((row & 7) << 4);
            *(s16x8*)((char*)Bsm + row * 128 + byt) = v;
        }
        __syncthreads();
#pragma unroll
        for (int ks = 0; ks < 2; ++ks) {
            s16x8 af[4], bf[4];
#pragma unroll
            for (int mi = 0; mi < 4; ++mi) {
                int row = wm * 64 + mi * 16 + (lane & 15);
                int byt = (ks * 64 + ((lane >> 4) * 16)) ^ ((row & 7) << 4);
                af[mi] = *(const s16x8*)((char*)Asm + row * 128 + byt);
            }
#pragma unroll
            for (int ni = 0; ni < 4; ++ni) {
                int row = wn * 64 + ni * 16 + (lane & 15);
                int byt = (ks * 64 + ((lane >> 4) * 16)) ^ ((row & 7) << 4);
                bf[ni] = *(const s16x8*)((char*)Bsm + row * 128 + byt);
            }
#pragma unroll
            for (int mi = 0; mi < 4; ++mi)
#pragma unroll
                for (int ni = 0; ni < 4; ++ni)
                    acc[mi][ni] = __builtin_amdgcn_mfma_f32_16x16x32_bf16(af[mi], bf[ni], acc[mi][ni], 0, 0, 0);
        }
        __syncthreads();
    }
#pragma unroll
    for (int mi = 0; mi < 4; ++mi) {
#pragma unroll
        for (int ni = 0; ni < 4; ++ni) {
            int ncol = wn * 64 + ni * 16 + (lane & 15);
            int col = colBase + ncol;
#pragma unroll
            for (int j = 0; j < 4; ++j) {
                int m = bm0 + wm * 64 + mi * 16 + (lane >> 4) * 4 + j;
                if (m < M) {
                    float v = acc[mi][ni][j] + bias[ncol];
                    if (mode == 0) {
                        v = fsigm(v) * bf2f(aux[(size_t)m * D + col]);
                        ((unsigned short*)outb)[(size_t)dir * outds + (size_t)m * ldo + col] = f2bf(v);
                    } else if (mode == 1) {
                        v = fmaxf(v, 0.f);
                        ((unsigned short*)outb)[(size_t)dir * outds + (size_t)m * ldo + col] = f2bf(v);
                    } else {
                        v = fmaxf(v, 0.f);
                        ((float*)outb)[(size_t)m * ldo + dir * ocolDS + col] = v;
                    }
                }
            }
        }
    }
}

// ---------------- per-sequence LSTM recurrence (packed f16 dot2, gate-interleaved) ----------------
__global__ __launch_bounds__(512, 2) void seq_lstm_k(const float* __restrict__ xgf,
                                                     const float* __restrict__ xgb,
                                                     const unsigned short* __restrict__ wseq,
                                                     const int* __restrict__ lens,
                                                     float* __restrict__ senc)
{
    int bid = blockIdx.x;
    int dir = bid >= BB ? 1 : 0;
    int b = dir ? bid - BB : bid;
    int len = lens[b];
    const float* xg = (dir ? xgb : xgf) + (size_t)b * LL * 512;
    const unsigned int* wp = (const unsigned int*)(wseq + dir * 131072);
    int tid = threadIdx.x;
    int q = tid & 3, unit = tid >> 2;
    unsigned int wreg[64];
#pragma unroll
    for (int k2 = 0; k2 < 64; ++k2) wreg[k2] = wp[k2 * 512 + tid];
    __shared__ __align__(16) unsigned short hlsq[2][128];
    float cj = 0.f;
    if (tid < 128) hlsq[0][tid] = 0;
    __syncthreads();
    float xcur = xg[tid];
    int pb = 0;
    for (int t = 0; t < len; ++t) {
        float xnext = (t + 1 < len) ? xg[(size_t)(t + 1) * 512 + tid] : 0.f;
        const uint4* hp = (const uint4*)&hlsq[pb][0];
        float p0 = 0.f, p1 = 0.f, p2 = 0.f, p3 = 0.f;
#pragma unroll
        for (int i = 0; i < 4; ++i) {
            uint4 h0 = hp[i * 4 + 0], h1 = hp[i * 4 + 1], h2 = hp[i * 4 + 2], h3 = hp[i * 4 + 3];
            const unsigned int* w0 = &wreg[i * 16];
            p0 = hdot(h0.x, w0[0], p0);  p0 = hdot(h0.y, w0[1], p0);
            p0 = hdot(h0.z, w0[2], p0);  p0 = hdot(h0.w, w0[3], p0);
            p1 = hdot(h1.x, w0[4], p1);  p1 = hdot(h1.y, w0[5], p1);
            p1 = hdot(h1.z, w0[6], p1);  p1 = hdot(h1.w, w0[7], p1);
            p2 = hdot(h2.x, w0[8], p2);  p2 = hdot(h2.y, w0[9], p2);
            p2 = hdot(h2.z, w0[10], p2); p2 = hdot(h2.w, w0[11], p2);
            p3 = hdot(h3.x, w0[12], p3); p3 = hdot(h3.y, w0[13], p3);
            p3 = hdot(h3.z, w0[14], p3); p3 = hdot(h3.w, w0[15], p3);
        }
        float accv = xcur + ((p0 + p1) + (p2 + p3));
        float tv = (q == 2) ? ftanh(accv) : fsigm(accv);
        float v1 = __shfl_xor(tv, 1), v2 = __shfl_xor(tv, 2), v3 = __shfl_xor(tv, 3);
        if (q == 0) {
            cj = v1 * cj + tv * v2;
            float hv = v3 * ftanh(cj);
            _Float16 hh = (_Float16)hv;
            hlsq[pb ^ 1][unit] = __builtin_bit_cast(unsigned short, hh);
            int tout = dir ? (len - 1 - t) : t;
            senc[((size_t)b * LL + tout) * 256 + dir * 128 + unit] = hv;
        }
        __syncthreads();
        pb ^= 1;
        xcur = xnext;
    }
}

// ---------------- mask + zero-invalid + max_len ----------------
__global__ __launch_bounds__(256) void finalize_k(const int* __restrict__ idx,
                                                  const int* __restrict__ lens,
                                                  float* __restrict__ senc,
                                                  float* __restrict__ mask,
                                                  float* __restrict__ omax,
                                                  const int* __restrict__ mlin)
{
    int id = blockIdx.x * 256 + threadIdx.x;
    if (id == 0) omax[0] = (float)mlin[0];
    if (id >= BB * LL * 64) return;
    int row = id >> 6, c = id & 63;
    int b = row / LL, tt = row % LL;
    if (c == 0) mask[row] = (idx[row] == 0) ? 1.f : 0.f;
    if (tt >= lens[b]) *(float4*)&senc[(size_t)row * 256 + c * 4] = make_float4(0.f, 0.f, 0.f, 0.f);
}

// ---------------- gated-attention context, dirs batched via grid.y ----------------
template<int D>
__global__ __launch_bounds__(256) void attn_ctx2_k(const unsigned short* __restrict__ hidb, int hidds,
                                                   const int* __restrict__ adj0, const int* __restrict__ adj1,
                                                   const float* __restrict__ a0f, const float* __restrict__ a0b,
                                                   const float* __restrict__ a1f, const float* __restrict__ a1b,
                                                   unsigned short* __restrict__ ctxb, int ctxds)
{
    constexpr int V = D / 64;
    int dir = blockIdx.y;
    const unsigned short* hid = hidb + (size_t)dir * hidds;
    const int* adj = dir ? adj1 : adj0;
    const float* att0 = dir ? a0b : a0f;
    const float* att1 = dir ? a1b : a1f;
    unsigned short* ctx = ctxb + (size_t)dir * ctxds;
    int lane = threadIdx.x & 63, wid = threadIdx.x >> 6;
    int n = blockIdx.x * 4 + wid;
    if (n >= NN) return;
    float a0[V], a1[V], sv[V];
#pragma unroll
    for (int j = 0; j < V; ++j) {
        a0[j] = att0[lane * V + j];
        a1[j] = att1[lane * V + j];
    }
    {
        if (V == 2) {
            unsigned int u = *(const unsigned int*)(hid + (size_t)n * D + lane * 2);
            sv[0] = bf2f(u); sv[1] = bf2f(u >> 16);
        } else {
            uint2 u = *(const uint2*)(hid + (size_t)n * D + lane * 4);
            sv[0] = bf2f(u.x); sv[1] = bf2f(u.x >> 16);
            sv[2] = bf2f(u.y); sv[3] = bf2f(u.y >> 16);
        }
    }
    float p = 0.f;
#pragma unroll
    for (int j = 0; j < V; ++j) p += sv[j] * a0[j];
#pragma unroll
    for (int m = 1; m < 64; m <<= 1) p += __shfl_xor(p, m);
    float s_self = p;
    float nv[KNB][V];
    float sc[KNB];
#pragma unroll
    for (int k = 0; k < KNB; ++k) {
        int nb = adj[n * KNB + k];
        float qv = 0.f;
        if (nb < NN) {
            if (V == 2) {
                unsigned int u = *(const unsigned int*)(hid + (size_t)nb * D + lane * 2);
                nv[k][0] = bf2f(u); nv[k][1] = bf2f(u >> 16);
            } else {
                uint2 u = *(const uint2*)(hid + (size_t)nb * D + lane * 4);
                nv[k][0] = bf2f(u.x); nv[k][1] = bf2f(u.x >> 16);
                nv[k][2] = bf2f(u.y); nv[k][3] = bf2f(u.y >> 16);
            }
        } else {
#pragma unroll
            for (int j = 0; j < V; ++j) nv[k][j] = 0.f;
        }
#pragma unroll
        for (int j = 0; j < V; ++j) qv += nv[k][j] * a1[j];
#pragma unroll
        for (int m = 1; m < 64; m <<= 1) qv += __shfl_xor(qv, m);
        sc[k] = s_self + qv;
    }
    float mx = sc[0];
#pragma unroll
    for (int k = 1; k < KNB; ++k) mx = fmaxf(mx, sc[k]);
    float s = 0.f;
#pragma unroll
    for (int k = 0; k < KNB; ++k) { sc[k] = fexp2((sc[k] - mx) * 1.4426950408889634f); s += sc[k]; }
    float inv = frcp(s);
#pragma unroll
    for (int j2 = 0; j2 < V; j2 += 2) {
        float c0 = 0.f, c1 = 0.f;
#pragma unroll
        for (int k = 0; k < KNB; ++k) { c0 += sc[k] * nv[k][j2]; c1 += sc[k] * nv[k][j2 + 1]; }
        unsigned int pk = (unsigned int)f2bf(c0 * inv) | ((unsigned int)f2bf(c1 * inv) << 16);
        *(unsigned int*)(ctx + (size_t)n * D + lane * V + j2) = pk;
    }
}

// ---------------- graph max pool: two-stage ----------------
__global__ __launch_bounds__(512) void gmax1_k(const float* __restrict__ gh, float* __restrict__ part)
{
    int g = blockIdx.x, ch = blockIdx.y;
    int c = threadIdx.x;
    const float* p = gh + ((size_t)g * 1000 + ch * (1000 / GCH)) * 512 + c;
    float m = -1e30f;
#pragma unroll 5
    for (int i = 0; i < 1000 / GCH; ++i) m = fmaxf(m, p[(size_t)i * 512]);
    part[((size_t)g * GCH + ch) * 512 + c] = m;
}

__global__ __launch_bounds__(512) void gmax2_k(const float* __restrict__ part, float* __restrict__ ge)
{
    int g = blockIdx.x;
    int c = threadIdx.x;
    float m = -1e30f;
#pragma unroll
    for (int i = 0; i < GCH; ++i) m = fmaxf(m, part[((size_t)g * GCH + i) * 512 + c]);
    ge[g * 512 + c] = m;
}

extern "C" void kernel_launch(void* const* d_in, const int* in_sizes, int n_in,
                              void* d_out, int out_size, void* d_ws, size_t ws_size,
                              hipStream_t stream)
{
    const float* embed = (const float*)d_in[0];
    const float* sfWhh = (const float*)d_in[2];
    const float* sfb   = (const float*)d_in[3];
    const float* sbWhh = (const float*)d_in[5];
    const float* sbb   = (const float*)d_in[6];
    const float* ndWih = (const float*)d_in[7];
    const float* ndWhh = (const float*)d_in[8];
    const float* ndb   = (const float*)d_in[9];
    const int* nodefeat = (const int*)d_in[30];
    const int* adj0     = (const int*)d_in[31];
    const int* adj1     = (const int*)d_in[32];
    const int* idxseq   = (const int*)d_in[33];
    const int* lens     = (const int*)d_in[34];
    const int* mlin     = (const int*)d_in[35];

    // ---- workspace layout (f32 offsets), phase-aliased; peak 23,581,440 f32 = 94.3 MB ----
    float* ws = (float*)d_ws;
    unsigned short* warena  = (unsigned short*)ws;                 // [0, 573,440) f32
    unsigned short* embedbf = (unsigned short*)(ws + 573440);      // [573,440, 2,621,440)
    float* xgf = ws + 2621440;                                     // [2,621,440, 5,898,240)
    float* xgb = ws + 5898240;                                     // [5,898,240, 9,175,040)
    int*   tokrev = (int*)(ws + 9175040);                          // [9,175,040, 9,181,440)
    float* cn = ws + 2621440;                                      // node cell (overlay xgf)
    unsigned short* hbf2 = (unsigned short*)(ws + 5898240);        // overlay xgb (3.2M us)
    unsigned short* hbf  = (unsigned short*)(ws + 9181440);        // [9,181,440, 10,781,440) persists
    // phase 3 (dir-strided, 2 dirs each):
    unsigned short* HA   = (unsigned short*)(ws + 573440);         // overlay embedbf+cn (12.8M us)
    unsigned short* HB   = (unsigned short*)(ws + 10781440);       // [10,781,440, 17,181,440)
    unsigned short* ctxb = (unsigned short*)(ws + 17181440);       // [17,181,440, 23,581,440) (gctx in-place)
    float* gmaxp = ws + 17181440;                                  // phase 4 partials (ctx dead)

    float* outf  = (float*)d_out;
    float* gh    = outf;                 // 12,800,000
    float* ge    = outf + 12800000;      // 12,800
    float* omax  = outf + 12812800;      // 1
    float* senc  = outf + 12812801;      // 1,638,400
    float* omask = outf + 14451201;      // 6,400

    // phase 0: preps
    tokrev_k<<<dim3((BB * LL + 255) / 256), dim3(256), 0, stream>>>(idxseq, lens, tokrev);
    embconv_k<<<dim3(VV * 128 / 256), dim3(256), 0, stream>>>(embed, embedbf);
    wprep_k<<<dim3(4480), dim3(256), 0, stream>>>(ndWih, ndWhh,
        (const float*)d_in[12], (const float*)d_in[14], (const float*)d_in[16], (const float*)d_in[18],
        (const float*)d_in[22], (const float*)d_in[24], (const float*)d_in[26], (const float*)d_in[28],
        (const float*)d_in[1], (const float*)d_in[4], sfWhh, sbWhh, warena);

    // phase 1: sequence bi-LSTM
    hgemm_k<1, 0, 1, 1><<<dim3(50, 4), dim3(256), 0, stream>>>(embedbf, 0, idxseq, 1, 0, nullptr,
        warena + 753664, sfb, xgf, 512, 0, BB * LL, 512, 128, nullptr);
    hgemm_k<1, 0, 1, 1><<<dim3(50, 4), dim3(256), 0, stream>>>(embedbf, 0, tokrev, 1, 0, nullptr,
        warena + 819200, sbb, xgb, 512, 0, BB * LL, 512, 128, nullptr);
    seq_lstm_k<<<dim3(2 * BB), dim3(512), 0, stream>>>(xgf, xgb, warena + 884736, lens, senc);
    finalize_k<<<dim3(1600), dim3(256), 0, stream>>>(idxseq, lens, senc, omask, omax, mlin);

    // phase 2: node LSTM (R5 structure: fused-cell GEMM x4, h ping-pong)
    zero_k<<<dim3((3200000 + 255) / 256), dim3(256), 0, stream>>>(cn, 3200000);
    zero_k<<<dim3((1600000 + 255) / 256), dim3(256), 0, stream>>>((float*)hbf, 1600000);
    for (int t = 0; t < NTK; ++t) {
        const unsigned short* hrd = (t & 1) ? hbf2 : hbf;
        unsigned short* hwr = (t & 1) ? hbf : hbf2;   // t=3 writes hbf (final)
        hgemm_k<2, 3, 0, 0><<<dim3(196, 4), dim3(256), 0, stream>>>(embedbf, 0, nodefeat, NTK, t, hrd,
            warena, ndb, hwr, 128, 0, NN, 512, 256, cn);
    }

    // phase 3: graph attention, fw+bw batched per launch
    for (int l = 0; l < 3; ++l) {
        int D = (l == 0) ? 128 : 256;
        int j = l - 1;
        const unsigned short* curb = (l == 0) ? hbf : (l == 1 ? HA : HB);
        int curds = (l == 0) ? 0 : NN * 256;
        int ctxds = NN * D;
        // attention pointers per dir
        const float* a0f = (l == 0) ? (const float*)d_in[10] : (const float*)d_in[11] + (size_t)j * 512;
        const float* a1f = (l == 0) ? (const float*)d_in[10] + 128 : (const float*)d_in[11] + (size_t)j * 512 + 256;
        const float* a0b = (l == 0) ? (const float*)d_in[20] : (const float*)d_in[21] + (size_t)j * 512;
        const float* a1b = (l == 0) ? (const float*)d_in[20] + 128 : (const float*)d_in[21] + (size_t)j * 512 + 256;

        if (D == 128)
            attn_ctx2_k<128><<<dim3(NN / 4, 2), dim3(256), 0, stream>>>(curb, curds, adj0, adj1,
                a0f, a0b, a1f, a1b, ctxb, ctxds);
        else
            attn_ctx2_k<256><<<dim3(NN / 4, 2), dim3(256), 0, stream>>>(curb, curds, adj0, adj1,
                a0f, a0b, a1f, a1b, ctxb, ctxds);

        // gate (in-place: ctx <- sigmoid(cur@Wg+bg)*ctx)
        const unsigned short* wgb = warena + 131072 + ((l == 0) ? 0 : 16384 + j * 65536);
        const float* bgf = (l == 0) ? (const float*)d_in[13] : (const float*)d_in[15] + (size_t)j * 256;
        const float* bgb = (l == 0) ? (const float*)d_in[23] : (const float*)d_in[25] + (size_t)j * 256;
        hgemm3_k<<<dim3(196, D / 128, 2), dim3(256), 0, stream>>>(curb, curds, nullptr, 0,
            wgb, 311296, 0, bgf, bgb, ctxb, ctxds, ctxb, ctxds, D, 0, NN, D, D, 0);

        // out: role 0 = relu(cur@Wo0+bo0), role 1 = relu(gctx@Wo1+bo1)
        const unsigned short* wob = warena + 131072 + ((l == 0) ? 147456 : 180224 + j * 65536);
        int wrs = (l == 0) ? 16384 : 32768;
        const float* bof = (l == 0) ? (const float*)d_in[17] : (const float*)d_in[19] + (size_t)j * 256;
        const float* bob = (l == 0) ? (const float*)d_in[27] : (const float*)d_in[29] + (size_t)j * 256;
        if (l == 2) {
            hgemm3_k<<<dim3(196, 2, 2), dim3(256), 0, stream>>>(curb, curds, ctxb, ctxds,
                wob, 311296, wrs, bof, bob, nullptr, 0, gh, 0, 512, 256, NN, D, D, 2);
        } else {
            unsigned short* ob = (l == 0) ? HA : HB;
            hgemm3_k<<<dim3(196, 2, 2), dim3(256), 0, stream>>>(curb, curds, ctxb, ctxds,
                wob, 311296, wrs, bof, bob, nullptr, 0, ob, NN * 256, 256, 0, NN, D, D, 1);
        }
    }

    // phase 4: graph embedding max-pool (two-stage)
    gmax1_k<<<dim3(NGRAPH, GCH), dim3(512), 0, stream>>>(gh, gmaxp);
    gmax2_k<<<dim3(NGRAPH), dim3(512), 0, stream>>>(gmaxp, ge);
}

// Round 8
// 803.963 us; speedup vs baseline: 1.5726x; 1.2614x over previous
//
#include <hip/hip_runtime.h>
#include <math.h>

#define NN 25000
#define KNB 16
#define HH 128
#define VV 32000
#define BB 50
#define LL 128
#define NTK 4
#define NGRAPH 25
#define GCH 20

typedef __attribute__((ext_vector_type(8))) short s16x8;
typedef __attribute__((ext_vector_type(4))) float f32x4;
typedef _Float16 h16x2 __attribute__((ext_vector_type(2)));

__device__ __forceinline__ float fexp2(float x) {
#if __has_builtin(__builtin_amdgcn_exp2f)
    return __builtin_amdgcn_exp2f(x);
#else
    return exp2f(x);
#endif
}
__device__ __forceinline__ float frcp(float x) {
#if __has_builtin(__builtin_amdgcn_rcpf)
    return __builtin_amdgcn_rcpf(x);
#else
    return 1.f / x;
#endif
}
__device__ __forceinline__ float fsigm(float x) { return frcp(1.f + fexp2(x * -1.4426950408889634f)); }
__device__ __forceinline__ float ftanh(float x) { return 1.f - 2.f * frcp(1.f + fexp2(x * 2.8853900817779268f)); }

__device__ __forceinline__ unsigned short f2bf(float x) {
    unsigned int u = __float_as_uint(x);
    unsigned int r = (u + 0x7fffu + ((u >> 16) & 1u)) >> 16;
    return (unsigned short)r;
}
__device__ __forceinline__ float bf2f(unsigned int b) {
    return __uint_as_float((b & 0xffffu) << 16);
}

// quad-lane xor exchange via DPP quad_perm (VALU, no LDS)
template<int CTRL>
__device__ __forceinline__ float qxor(float x) {
#if __has_builtin(__builtin_amdgcn_mov_dpp)
    return __int_as_float(__builtin_amdgcn_mov_dpp(__float_as_int(x), CTRL, 0xf, 0xf, true));
#else
    int m = (CTRL == 0xB1) ? 1 : (CTRL == 0x4E) ? 2 : 3;
    return __shfl_xor(x, m, 64);
#endif
}

// packed f16 dot2
__device__ __forceinline__ float hdot(unsigned int a, unsigned int b, float c) {
#if __has_builtin(__builtin_amdgcn_fdot2)
    return __builtin_amdgcn_fdot2(__builtin_bit_cast(h16x2, a), __builtin_bit_cast(h16x2, b), c, false);
#else
    h16x2 av = __builtin_bit_cast(h16x2, a), bv = __builtin_bit_cast(h16x2, b);
    return c + (float)av[0] * (float)bv[0] + (float)av[1] * (float)bv[1];
#endif
}

__global__ __launch_bounds__(256) void zero_k(float* __restrict__ p, int n)
{
    int i = blockIdx.x * 256 + threadIdx.x;
    if (i < n) p[i] = 0.f;
}

// ---------------- embed f32 -> bf16 ----------------
__global__ __launch_bounds__(256) void embconv_k(const float* __restrict__ e,
                                                 unsigned short* __restrict__ o)
{
    int i = blockIdx.x * 256 + threadIdx.x;
    if (i < VV * 128) o[i] = f2bf(e[i]);
}

// ---------------- weight prep (same arena layout as R5) ----------------
__global__ __launch_bounds__(256) void wprep_k(
    const float* __restrict__ ndWih, const float* __restrict__ ndWhh,
    const float* __restrict__ fWg0, const float* __restrict__ fWgr,
    const float* __restrict__ fWo0, const float* __restrict__ fWor,
    const float* __restrict__ bWg0, const float* __restrict__ bWgr,
    const float* __restrict__ bWo0, const float* __restrict__ bWor,
    const float* __restrict__ sfWih, const float* __restrict__ sbWih,
    const float* __restrict__ sfWhh, const float* __restrict__ sbWhh,
    unsigned short* __restrict__ dst)
{
    int idx = blockIdx.x * 256 + threadIdx.x;
    if (idx >= 1146880) return;
    if (idx >= 884736) {
        int r = idx - 884736;
        int d = r >> 17;
        int o = r & 131071;
        int pairIdx = o >> 1, hf = o & 1;
        int k2 = pairIdx >> 9, n = pairIdx & 511;
        int k = k2 * 2 + hf;
        int unit = n >> 2, gate = n & 3;
        const float* W = d ? sbWhh : sfWhh;
        _Float16 hv = (_Float16)W[(gate * 128 + unit) * 128 + k];
        dst[idx] = __builtin_bit_cast(unsigned short, hv);
        return;
    }
    float val;
    if (idx < 131072) {
        int r = idx >> 8, k = idx & 255;
        int unit = r >> 2, gate = r & 3;
        int srow = (gate << 7) + unit;
        val = (k < 128) ? ndWih[srow * 128 + k] : ndWhh[srow * 128 + (k - 128)];
    } else if (idx < 753664) {
        int r = idx - 131072;
        int dir = r / 311296;
        int o = r % 311296;
        const float* Wg0 = dir ? bWg0 : fWg0;
        const float* Wgr = dir ? bWgr : fWgr;
        const float* Wo0 = dir ? bWo0 : fWo0;
        const float* Wor = dir ? bWor : fWor;
        if (o < 16384) {
            int n = o >> 7, k = o & 127;
            val = Wg0[k * 128 + n];
        } else if (o < 147456) {
            int p = o - 16384;
            int j = p >> 16, q = p & 65535;
            int n = q >> 8, k = q & 255;
            val = Wgr[j * 65536 + k * 256 + n];
        } else if (o < 180224) {
            int p = o - 147456;
            int s = p >> 14, q = p & 16383;
            int n = q >> 7, k = q & 127;
            val = Wo0[s * 16384 + k * 128 + n];
        } else {
            int p = o - 180224;
            int js = p >> 15, q = p & 32767;
            int n = q >> 8, k = q & 255;
            val = Wor[js * 32768 + k * 128 + n];
        }
    } else if (idx < 819200) {
        val = sfWih[idx - 753664];
    } else {
        val = sbWih[idx - 819200];
    }
    dst[idx] = f2bf(val);
}

__global__ __launch_bounds__(256) void tokrev_k(const int* __restrict__ idx,
                                                const int* __restrict__ lens,
                                                int* __restrict__ tokrev)
{
    int t = blockIdx.x * 256 + threadIdx.x;
    if (t >= BB * LL) return;
    int b = t / LL, tt = t % LL;
    int r = lens[b] - 1 - tt;
    r = r < 0 ? 0 : (r > LL - 1 ? LL - 1 : r);
    tokrev[t] = idx[b * LL + r];
}

// ---------------- bf16 MFMA GEMM (phase 1 + node phase) ----------------
// AMODE 1: embed_bf[gidx[m*gs+go]*128+k]; 2: k<128 embed else H2[m*128+k-128]
// EP 0: none; 3: fused LSTM cell (gate-interleaved N, dense lane-owned c)
// OF32 1: out f32 ; PERM 1: permute out col n -> unit*4+gate
template<int AMODE, int EP, int OF32, int PERM>
__global__ __launch_bounds__(256) void hgemm_k(
    const unsigned short* __restrict__ A, int lda,
    const int* __restrict__ gidx, int gstride, int goff,
    const unsigned short* __restrict__ H2,
    const unsigned short* __restrict__ Wt,   // [N][K] bf16
    const float* __restrict__ bias,
    void* __restrict__ outp, int ldo, int ocol,
    int M, int N, int K, float* __restrict__ cbuf)
{
    __shared__ unsigned short Asm[128 * 64];
    __shared__ unsigned short Bsm[128 * 64];
    const int tid = threadIdx.x;
    const int lane = tid & 63, w = tid >> 6;
    const int wm = w >> 1, wn = w & 1;
    const int lane15 = lane & 15, hi = lane >> 4, q = lane & 3;
    const int bm0 = blockIdx.x * 128, bn0 = blockIdx.y * 128;
    f32x4 acc[4][4];
#pragma unroll
    for (int i = 0; i < 4; ++i)
#pragma unroll
        for (int j = 0; j < 4; ++j) acc[i][j] = (f32x4){0.f, 0.f, 0.f, 0.f};

    for (int kt = 0; kt < K; kt += 64) {
#pragma unroll
        for (int r = 0; r < 4; ++r) {
            int id = tid + r * 256;
            int row = id >> 3, cc = id & 7;
            int m = bm0 + row;
            s16x8 v = {0, 0, 0, 0, 0, 0, 0, 0};
            if (m < M) {
                const unsigned short* src;
                if (AMODE == 1) {
                    int g = gidx[m * gstride + goff];
                    src = A + (size_t)g * 128 + kt + cc * 8;
                } else {
                    int k0 = kt + cc * 8;
                    if (k0 < 128) {
                        int g = gidx[m * gstride + goff];
                        src = A + (size_t)g * 128 + k0;
                    } else {
                        src = H2 + (size_t)m * 128 + (k0 - 128);
                    }
                }
                v = *(const s16x8*)src;
            }
            int byt = (cc * 16) ^ ((row & 7) << 4);
            *(s16x8*)((char*)Asm + row * 128 + byt) = v;
        }
#pragma unroll
        for (int r = 0; r < 4; ++r) {
            int id = tid + r * 256;
            int row = id >> 3, cc = id & 7;
            s16x8 v = *(const s16x8*)(Wt + (size_t)(bn0 + row) * K + kt + cc * 8);
            int byt = (cc * 16) ^ ((row & 7) << 4);
            *(s16x8*)((char*)Bsm + row * 128 + byt) = v;
        }
        __syncthreads();
#pragma unroll
        for (int ks = 0; ks < 2; ++ks) {
            s16x8 af[4], bf[4];
#pragma unroll
            for (int mi = 0; mi < 4; ++mi) {
                int row = wm * 64 + mi * 16 + lane15;
                int byt = (ks * 64 + (hi * 16)) ^ ((row & 7) << 4);
                af[mi] = *(const s16x8*)((char*)Asm + row * 128 + byt);
            }
#pragma unroll
            for (int ni = 0; ni < 4; ++ni) {
                int row = wn * 64 + ni * 16 + lane15;
                int byt = (ks * 64 + (hi * 16)) ^ ((row & 7) << 4);
                bf[ni] = *(const s16x8*)((char*)Bsm + row * 128 + byt);
            }
#pragma unroll
            for (int mi = 0; mi < 4; ++mi)
#pragma unroll
                for (int ni = 0; ni < 4; ++ni)
                    acc[mi][ni] = __builtin_amdgcn_mfma_f32_16x16x32_bf16(af[mi], bf[ni], acc[mi][ni], 0, 0, 0);
        }
        __syncthreads();
    }
    if (EP == 3) {
        // dense lane-owned c: 16 floats per (block, wave, lane)
        float* cb = cbuf + ((((size_t)(blockIdx.y * gridDim.x + blockIdx.x)) * 4 + w) * 64 + lane) * 16;
        f32x4 cr[4];
#pragma unroll
        for (int i = 0; i < 4; ++i) cr[i] = *(f32x4*)(cb + i * 4);
        const bool qb0 = (lane & 1), qb1 = (lane & 2);
#pragma unroll
        for (int mi = 0; mi < 4; ++mi) {
#pragma unroll
            for (int ni = 0; ni < 4; ++ni) {
                int n = bn0 + wn * 64 + ni * 16 + lane15;
                int unit = n >> 2;
                float bval = bias[((n & 3) << 7) + unit];
#pragma unroll
                for (int j = 0; j < 4; ++j) {
                    float v = acc[mi][ni][j] + bval;
                    float tv = (q == 2) ? ftanh(v) : fsigm(v);
                    float v1 = qxor<0xB1>(tv), v2 = qxor<0x4E>(tv), v3 = qxor<0x1B>(tv);
                    if (q == j) {
                        // XOR-group remap: gate g lives in reg index q^g
                        float gf = qb0 ? (qb1 ? v2 : tv) : (qb1 ? v3 : v1);   // gate1
                        float gig = qb0 ? (v1 * v3) : (tv * v2);              // gate0*gate2
                        float go = qb0 ? (qb1 ? tv : v2) : (qb1 ? v1 : v3);   // gate3
                        float cc = gf * cr[mi][ni] + gig;
                        cr[mi][ni] = cc;
                        int m = bm0 + wm * 64 + mi * 16 + hi * 4 + j;
                        if (m < M) ((unsigned short*)outp)[(size_t)m * HH + unit] = f2bf(go * ftanh(cc));
                    }
                }
            }
        }
#pragma unroll
        for (int i = 0; i < 4; ++i) *(f32x4*)(cb + i * 4) = cr[i];
    } else {
#pragma unroll
        for (int mi = 0; mi < 4; ++mi) {
#pragma unroll
            for (int ni = 0; ni < 4; ++ni) {
                int n = bn0 + wn * 64 + ni * 16 + lane15;
#pragma unroll
                for (int j = 0; j < 4; ++j) {
                    int m = bm0 + wm * 64 + mi * 16 + hi * 4 + j;
                    if (m < M) {
                        float v = acc[mi][ni][j] + bias[n];
                        int nn = PERM ? (((n & 127) << 2) | (n >> 7)) : n;
                        if (OF32) ((float*)outp)[(size_t)m * ldo + ocol + nn] = v;
                        else ((unsigned short*)outp)[(size_t)m * ldo + ocol + nn] = f2bf(v);
                    }
                }
            }
        }
    }
}

// ---------------- phase-3 batched GEMM (unchanged from R7) ----------------
__global__ __launch_bounds__(256) void hgemm3_k(
    const unsigned short* __restrict__ A0, int a0ds,
    const unsigned short* __restrict__ A1, int a1ds,
    const unsigned short* __restrict__ Wb, int wds, int wrs,
    const float* __restrict__ b0, const float* __restrict__ b1,
    const unsigned short* __restrict__ auxb, int auxds,
    void* __restrict__ outb, int outds, int ldo, int ocolDS,
    int M, int K, int D, int mode)
{
    __shared__ unsigned short Asm[128 * 64];
    __shared__ unsigned short Bsm[128 * 64];
    const int tid = threadIdx.x;
    const int lane = tid & 63, w = tid >> 6;
    const int wm = w >> 1, wn = w & 1;
    const int bm0 = blockIdx.x * 128;
    const int dir = blockIdx.z, y = blockIdx.y;
    const int colBase = y * 128;
    const unsigned short* A = (mode == 0 || y == 0) ? (A0 + (size_t)dir * a0ds)
                                                    : (A1 + (size_t)dir * a1ds);
    const unsigned short* Wt = Wb + (size_t)dir * wds
                             + ((mode == 0) ? (size_t)colBase * K : (size_t)y * wrs);
    const float* bias = (dir ? b1 : b0) + colBase;
    const unsigned short* aux = auxb ? (auxb + (size_t)dir * auxds) : nullptr;

    f32x4 acc[4][4];
#pragma unroll
    for (int i = 0; i < 4; ++i)
#pragma unroll
        for (int j = 0; j < 4; ++j) acc[i][j] = (f32x4){0.f, 0.f, 0.f, 0.f};

    for (int kt = 0; kt < K; kt += 64) {
#pragma unroll
        for (int r = 0; r < 4; ++r) {
            int id = tid + r * 256;
            int row = id >> 3, cc = id & 7;
            int m = bm0 + row;
            s16x8 v = {0, 0, 0, 0, 0, 0, 0, 0};
            if (m < M) v = *(const s16x8*)(A + (size_t)m * K + kt + cc * 8);
            int byt = (cc * 16) ^ ((row & 7) << 4);
            *(s16x8*)((char*)Asm + row * 128 + byt) = v;
        }
#pragma unroll
        for (int r = 0; r < 4; ++r) {
            int id = tid + r * 256;
            int row = id >> 3, cc = id & 7;
            s16x8 v = *(const s16x8*)(Wt + (size_t)row * K + kt + cc * 8);
            int byt = (cc * 16) ^ ((row & 7) << 4);
            *(s16x8*)((char*)Bsm + row * 128 + byt) = v;
        }
        __syncthreads();
#pragma unroll
        for (int ks = 0; ks < 2; ++ks) {
            s16x8 af[4], bf[4];
#pragma unroll
            for (int mi = 0; mi < 4; ++mi) {
                int row = wm * 64 + mi * 16 + (lane & 15);
                int byt = (ks * 64 + ((lane >> 4) * 16)) ^ ((row & 7) << 4);
                af[mi] = *(const s16x8*)((char*)Asm + row * 128 + byt);
            }
#pragma unroll
            for (int ni = 0; ni < 4; ++ni) {
                int row = wn * 64 + ni * 16 + (lane & 15);
                int byt = (ks * 64 + ((lane >> 4) * 16)) ^ ((row & 7) << 4);
                bf[ni] = *(const s16x8*)((char*)Bsm + row * 128 + byt);
            }
#pragma unroll
            for (int mi = 0; mi < 4; ++mi)
#pragma unroll
                for (int ni = 0; ni < 4; ++ni)
                    acc[mi][ni] = __builtin_amdgcn_mfma_f32_16x16x32_bf16(af[mi], bf[ni], acc[mi][ni], 0, 0, 0);
        }
        __syncthreads();
    }
#pragma unroll
    for (int mi = 0; mi < 4; ++mi) {
#pragma unroll
        for (int ni = 0; ni < 4; ++ni) {
            int ncol = wn * 64 + ni * 16 + (lane & 15);
            int col = colBase + ncol;
#pragma unroll
            for (int j = 0; j < 4; ++j) {
                int m = bm0 + wm * 64 + mi * 16 + (lane >> 4) * 4 + j;
                if (m < M) {
                    float v = acc[mi][ni][j] + bias[ncol];
                    if (mode == 0) {
                        v = fsigm(v) * bf2f(aux[(size_t)m * D + col]);
                        ((unsigned short*)outb)[(size_t)dir * outds + (size_t)m * ldo + col] = f2bf(v);
                    } else if (mode == 1) {
                        v = fmaxf(v, 0.f);
                        ((unsigned short*)outb)[(size_t)dir * outds + (size_t)m * ldo + col] = f2bf(v);
                    } else {
                        v = fmaxf(v, 0.f);
                        ((float*)outb)[(size_t)m * ldo + dir * ocolDS + col] = v;
                    }
                }
            }
        }
    }
}

// ---------------- per-sequence LSTM recurrence (unchanged) ----------------
__global__ __launch_bounds__(512, 2) void seq_lstm_k(const float* __restrict__ xgf,
                                                     const float* __restrict__ xgb,
                                                     const unsigned short* __restrict__ wseq,
                                                     const int* __restrict__ lens,
                                                     float* __restrict__ senc)
{
    int bid = blockIdx.x;
    int dir = bid >= BB ? 1 : 0;
    int b = dir ? bid - BB : bid;
    int len = lens[b];
    const float* xg = (dir ? xgb : xgf) + (size_t)b * LL * 512;
    const unsigned int* wp = (const unsigned int*)(wseq + dir * 131072);
    int tid = threadIdx.x;
    int q = tid & 3, unit = tid >> 2;
    unsigned int wreg[64];
#pragma unroll
    for (int k2 = 0; k2 < 64; ++k2) wreg[k2] = wp[k2 * 512 + tid];
    __shared__ __align__(16) unsigned short hlsq[2][128];
    float cj = 0.f;
    if (tid < 128) hlsq[0][tid] = 0;
    __syncthreads();
    float xcur = xg[tid];
    int pb = 0;
    for (int t = 0; t < len; ++t) {
        float xnext = (t + 1 < len) ? xg[(size_t)(t + 1) * 512 + tid] : 0.f;
        const uint4* hp = (const uint4*)&hlsq[pb][0];
        float p0 = 0.f, p1 = 0.f, p2 = 0.f, p3 = 0.f;
#pragma unroll
        for (int i = 0; i < 4; ++i) {
            uint4 h0 = hp[i * 4 + 0], h1 = hp[i * 4 + 1], h2 = hp[i * 4 + 2], h3 = hp[i * 4 + 3];
            const unsigned int* w0 = &wreg[i * 16];
            p0 = hdot(h0.x, w0[0], p0);  p0 = hdot(h0.y, w0[1], p0);
            p0 = hdot(h0.z, w0[2], p0);  p0 = hdot(h0.w, w0[3], p0);
            p1 = hdot(h1.x, w0[4], p1);  p1 = hdot(h1.y, w0[5], p1);
            p1 = hdot(h1.z, w0[6], p1);  p1 = hdot(h1.w, w0[7], p1);
            p2 = hdot(h2.x, w0[8], p2);  p2 = hdot(h2.y, w0[9], p2);
            p2 = hdot(h2.z, w0[10], p2); p2 = hdot(h2.w, w0[11], p2);
            p3 = hdot(h3.x, w0[12], p3); p3 = hdot(h3.y, w0[13], p3);
            p3 = hdot(h3.z, w0[14], p3); p3 = hdot(h3.w, w0[15], p3);
        }
        float accv = xcur + ((p0 + p1) + (p2 + p3));
        float tv = (q == 2) ? ftanh(accv) : fsigm(accv);
        float v1 = __shfl_xor(tv, 1), v2 = __shfl_xor(tv, 2), v3 = __shfl_xor(tv, 3);
        if (q == 0) {
            cj = v1 * cj + tv * v2;
            float hv = v3 * ftanh(cj);
            _Float16 hh = (_Float16)hv;
            hlsq[pb ^ 1][unit] = __builtin_bit_cast(unsigned short, hh);
            int tout = dir ? (len - 1 - t) : t;
            senc[((size_t)b * LL + tout) * 256 + dir * 128 + unit] = hv;
        }
        __syncthreads();
        pb ^= 1;
        xcur = xnext;
    }
}

// ---------------- mask + zero-invalid + max_len ----------------
__global__ __launch_bounds__(256) void finalize_k(const int* __restrict__ idx,
                                                  const int* __restrict__ lens,
                                                  float* __restrict__ senc,
                                                  float* __restrict__ mask,
                                                  float* __restrict__ omax,
                                                  const int* __restrict__ mlin)
{
    int id = blockIdx.x * 256 + threadIdx.x;
    if (id == 0) omax[0] = (float)mlin[0];
    if (id >= BB * LL * 64) return;
    int row = id >> 6, c = id & 63;
    int b = row / LL, tt = row % LL;
    if (c == 0) mask[row] = (idx[row] == 0) ? 1.f : 0.f;
    if (tt >= lens[b]) *(float4*)&senc[(size_t)row * 256 + c * 4] = make_float4(0.f, 0.f, 0.f, 0.f);
}

// ---------------- s1[n] = hid[n,:]·att1 precompute (dirs via grid.y) ----------------
template<int D>
__global__ __launch_bounds__(256) void sdot_k(const unsigned short* __restrict__ hidb, int hidds,
                                              const float* __restrict__ a1f, const float* __restrict__ a1b,
                                              float* __restrict__ s1)
{
    constexpr int V = D / 64;
    int dir = blockIdx.y;
    const unsigned short* hid = hidb + (size_t)dir * hidds;
    const float* att1 = dir ? a1b : a1f;
    int lane = threadIdx.x & 63, wid = threadIdx.x >> 6;
    int n = blockIdx.x * 4 + wid;
    if (n >= NN) return;
    float p = 0.f;
    if (V == 2) {
        unsigned int u = *(const unsigned int*)(hid + (size_t)n * D + lane * 2);
        p = bf2f(u) * att1[lane * 2] + bf2f(u >> 16) * att1[lane * 2 + 1];
    } else {
        uint2 u = *(const uint2*)(hid + (size_t)n * D + lane * 4);
        p = bf2f(u.x) * att1[lane * 4] + bf2f(u.x >> 16) * att1[lane * 4 + 1]
          + bf2f(u.y) * att1[lane * 4 + 2] + bf2f(u.y >> 16) * att1[lane * 4 + 3];
    }
#pragma unroll
    for (int m = 1; m < 64; m <<= 1) p += __shfl_xor(p, m);
    if (lane == 0) s1[dir * NN + n] = p;
}

// ---------------- gated-attention context v3: scalar scores, single row-gather pass ----------------
template<int D>
__global__ __launch_bounds__(256) void attn_ctx3_k(const unsigned short* __restrict__ hidb, int hidds,
                                                   const int* __restrict__ adj0, const int* __restrict__ adj1,
                                                   const float* __restrict__ s1,
                                                   unsigned short* __restrict__ ctxb, int ctxds)
{
    constexpr int V = D / 64;
    int dir = blockIdx.y;
    const unsigned short* hid = hidb + (size_t)dir * hidds;
    const int* adj = dir ? adj1 : adj0;
    unsigned short* ctx = ctxb + (size_t)dir * ctxds;
    int lane = threadIdx.x & 63, wid = threadIdx.x >> 6;
    int n = blockIdx.x * 4 + wid;
    if (n >= NN) return;
    int nb[KNB];
    float sc[KNB];
#pragma unroll
    for (int k = 0; k < KNB; ++k) nb[k] = adj[n * KNB + k];
#pragma unroll
    for (int k = 0; k < KNB; ++k) sc[k] = (nb[k] < NN) ? s1[dir * NN + nb[k]] : 0.f;
    // softmax over 16 scalars (self-score is k-constant -> cancels)
    float mx = sc[0];
#pragma unroll
    for (int k = 1; k < KNB; ++k) mx = fmaxf(mx, sc[k]);
    float s = 0.f;
#pragma unroll
    for (int k = 0; k < KNB; ++k) { sc[k] = fexp2((sc[k] - mx) * 1.4426950408889634f); s += sc[k]; }
    float inv = frcp(s);
    float accv[V];
#pragma unroll
    for (int j = 0; j < V; ++j) accv[j] = 0.f;
#pragma unroll
    for (int k = 0; k < KNB; ++k) {
        if (nb[k] < NN) {
            if (V == 2) {
                unsigned int u = *(const unsigned int*)(hid + (size_t)nb[k] * D + lane * 2);
                accv[0] += sc[k] * bf2f(u);
                accv[1] += sc[k] * bf2f(u >> 16);
            } else {
                uint2 u = *(const uint2*)(hid + (size_t)nb[k] * D + lane * 4);
                accv[0] += sc[k] * bf2f(u.x);
                accv[1] += sc[k] * bf2f(u.x >> 16);
                accv[2] += sc[k] * bf2f(u.y);
                accv[3] += sc[k] * bf2f(u.y >> 16);
            }
        }
    }
#pragma unroll
    for (int j2 = 0; j2 < V; j2 += 2) {
        unsigned int pk = (unsigned int)f2bf(accv[j2] * inv) | ((unsigned int)f2bf(accv[j2 + 1] * inv) << 16);
        *(unsigned int*)(ctx + (size_t)n * D + lane * V + j2) = pk;
    }
}

// ---------------- graph max pool: two-stage ----------------
__global__ __launch_bounds__(512) void gmax1_k(const float* __restrict__ gh, float* __restrict__ part)
{
    int g = blockIdx.x, ch = blockIdx.y;
    int c = threadIdx.x;
    const float* p = gh + ((size_t)g * 1000 + ch * (1000 / GCH)) * 512 + c;
    float m = -1e30f;
#pragma unroll 5
    for (int i = 0; i < 1000 / GCH; ++i) m = fmaxf(m, p[(size_t)i * 512]);
    part[((size_t)g * GCH + ch) * 512 + c] = m;
}

__global__ __launch_bounds__(512) void gmax2_k(const float* __restrict__ part, float* __restrict__ ge)
{
    int g = blockIdx.x;
    int c = threadIdx.x;
    float m = -1e30f;
#pragma unroll
    for (int i = 0; i < GCH; ++i) m = fmaxf(m, part[((size_t)g * GCH + i) * 512 + c]);
    ge[g * 512 + c] = m;
}

extern "C" void kernel_launch(void* const* d_in, const int* in_sizes, int n_in,
                              void* d_out, int out_size, void* d_ws, size_t ws_size,
                              hipStream_t stream)
{
    const float* embed = (const float*)d_in[0];
    const float* sfWhh = (const float*)d_in[2];
    const float* sfb   = (const float*)d_in[3];
    const float* sbWhh = (const float*)d_in[5];
    const float* sbb   = (const float*)d_in[6];
    const float* ndWih = (const float*)d_in[7];
    const float* ndWhh = (const float*)d_in[8];
    const float* ndb   = (const float*)d_in[9];
    const int* nodefeat = (const int*)d_in[30];
    const int* adj0     = (const int*)d_in[31];
    const int* adj1     = (const int*)d_in[32];
    const int* idxseq   = (const int*)d_in[33];
    const int* lens     = (const int*)d_in[34];
    const int* mlin     = (const int*)d_in[35];

    // ---- workspace layout (f32 offsets), phase-aliased; peak ~23.64M f32 = 94.6 MB ----
    float* ws = (float*)d_ws;
    unsigned short* warena  = (unsigned short*)ws;                 // [0, 573,440)
    unsigned short* embedbf = (unsigned short*)(ws + 573440);      // [573,440, 2,621,440)
    float* xgf = ws + 2621440;                                     // [2,621,440, 5,898,240)
    float* xgb = ws + 5898240;                                     // [5,898,240, 9,175,040)
    int*   tokrev = (int*)(ws + 9175040);                          // [9,175,040, 9,181,440)
    unsigned short* hbf2 = (unsigned short*)(ws + 5898240);        // overlay xgb (3.2M us)
    unsigned short* hbf  = (unsigned short*)(ws + 9181440);        // [9,181,440, 10,781,440) persists
    float* cbuf = ws + 10781440;                                   // node c: 3,211,264 f32 (overlaid by HB later)
    // phase 3 (dir-strided):
    unsigned short* HA   = (unsigned short*)(ws + 573440);         // overlay embedbf (12.8M us)
    unsigned short* HB   = (unsigned short*)(ws + 10781440);       // [10,781,440, 17,181,440)
    unsigned short* ctxb = (unsigned short*)(ws + 17181440);       // [17,181,440, 23,581,440)
    float* s1buf = ws + 23581440;                                  // [23,581,440, 23,631,440)
    float* gmaxp = ws + 17181440;                                  // phase 4 partials (ctx dead)

    float* outf  = (float*)d_out;
    float* gh    = outf;                 // 12,800,000
    float* ge    = outf + 12800000;      // 12,800
    float* omax  = outf + 12812800;      // 1
    float* senc  = outf + 12812801;      // 1,638,400
    float* omask = outf + 14451201;      // 6,400

    // phase 0: preps
    tokrev_k<<<dim3((BB * LL + 255) / 256), dim3(256), 0, stream>>>(idxseq, lens, tokrev);
    embconv_k<<<dim3(VV * 128 / 256), dim3(256), 0, stream>>>(embed, embedbf);
    wprep_k<<<dim3(4480), dim3(256), 0, stream>>>(ndWih, ndWhh,
        (const float*)d_in[12], (const float*)d_in[14], (const float*)d_in[16], (const float*)d_in[18],
        (const float*)d_in[22], (const float*)d_in[24], (const float*)d_in[26], (const float*)d_in[28],
        (const float*)d_in[1], (const float*)d_in[4], sfWhh, sbWhh, warena);

    // phase 1: sequence bi-LSTM
    hgemm_k<1, 0, 1, 1><<<dim3(50, 4), dim3(256), 0, stream>>>(embedbf, 0, idxseq, 1, 0, nullptr,
        warena + 753664, sfb, xgf, 512, 0, BB * LL, 512, 128, nullptr);
    hgemm_k<1, 0, 1, 1><<<dim3(50, 4), dim3(256), 0, stream>>>(embedbf, 0, tokrev, 1, 0, nullptr,
        warena + 819200, sbb, xgb, 512, 0, BB * LL, 512, 128, nullptr);
    seq_lstm_k<<<dim3(2 * BB), dim3(512), 0, stream>>>(xgf, xgb, warena + 884736, lens, senc);
    finalize_k<<<dim3(1600), dim3(256), 0, stream>>>(idxseq, lens, senc, omask, omax, mlin);

    // phase 2: node LSTM (fused-cell GEMM x4, dense lane-owned c, h ping-pong)
    zero_k<<<dim3((3211264 + 255) / 256), dim3(256), 0, stream>>>(cbuf, 3211264);
    zero_k<<<dim3((1600000 + 255) / 256), dim3(256), 0, stream>>>((float*)hbf, 1600000);
    for (int t = 0; t < NTK; ++t) {
        const unsigned short* hrd = (t & 1) ? hbf2 : hbf;
        unsigned short* hwr = (t & 1) ? hbf : hbf2;   // t=3 writes hbf (final)
        hgemm_k<2, 3, 0, 0><<<dim3(196, 4), dim3(256), 0, stream>>>(embedbf, 0, nodefeat, NTK, t, hrd,
            warena, ndb, hwr, 128, 0, NN, 512, 256, cbuf);
    }

    // phase 3: graph attention, fw+bw batched per launch
    for (int l = 0; l < 3; ++l) {
        int D = (l == 0) ? 128 : 256;
        int j = l - 1;
        const unsigned short* curb = (l == 0) ? hbf : (l == 1 ? HA : HB);
        int curds = (l == 0) ? 0 : NN * 256;
        int ctxds = NN * D;
        const float* a1f = (l == 0) ? (const float*)d_in[10] + 128 : (const float*)d_in[11] + (size_t)j * 512 + 256;
        const float* a1b = (l == 0) ? (const float*)d_in[20] + 128 : (const float*)d_in[21] + (size_t)j * 512 + 256;

        if (D == 128) {
            sdot_k<128><<<dim3(NN / 4, 2), dim3(256), 0, stream>>>(curb, curds, a1f, a1b, s1buf);
            attn_ctx3_k<128><<<dim3(NN / 4, 2), dim3(256), 0, stream>>>(curb, curds, adj0, adj1, s1buf, ctxb, ctxds);
        } else {
            sdot_k<256><<<dim3(NN / 4, 2), dim3(256), 0, stream>>>(curb, curds, a1f, a1b, s1buf);
            attn_ctx3_k<256><<<dim3(NN / 4, 2), dim3(256), 0, stream>>>(curb, curds, adj0, adj1, s1buf, ctxb, ctxds);
        }

        // gate (in-place: ctx <- sigmoid(cur@Wg+bg)*ctx)
        const unsigned short* wgb = warena + 131072 + ((l == 0) ? 0 : 16384 + j * 65536);
        const float* bgf = (l == 0) ? (const float*)d_in[13] : (const float*)d_in[15] + (size_t)j * 256;
        const float* bgb = (l == 0) ? (const float*)d_in[23] : (const float*)d_in[25] + (size_t)j * 256;
        hgemm3_k<<<dim3(196, D / 128, 2), dim3(256), 0, stream>>>(curb, curds, nullptr, 0,
            wgb, 311296, 0, bgf, bgb, ctxb, ctxds, ctxb, ctxds, D, 0, NN, D, D, 0);

        // out: role 0 = relu(cur@Wo0+bo0), role 1 = relu(gctx@Wo1+bo1)
        const unsigned short* wob = warena + 131072 + ((l == 0) ? 147456 : 180224 + j * 65536);
        int wrs = (l == 0) ? 16384 : 32768;
        const float* bof = (l == 0) ? (const float*)d_in[17] : (const float*)d_in[19] + (size_t)j * 256;
        const float* bob = (l == 0) ? (const float*)d_in[27] : (const float*)d_in[29] + (size_t)j * 256;
        if (l == 2) {
            hgemm3_k<<<dim3(196, 2, 2), dim3(256), 0, stream>>>(curb, curds, ctxb, ctxds,
                wob, 311296, wrs, bof, bob, nullptr, 0, gh, 0, 512, 256, NN, D, D, 2);
        } else {
            unsigned short* ob = (l == 0) ? HA : HB;
            hgemm3_k<<<dim3(196, 2, 2), dim3(256), 0, stream>>>(curb, curds, ctxb, ctxds,
                wob, 311296, wrs, bof, bob, nullptr, 0, ob, NN * 256, 256, 0, NN, D, D, 1);
        }
    }

    // phase 4: graph embedding max-pool (two-stage)
    gmax1_k<<<dim3(NGRAPH, GCH), dim3(512), 0, stream>>>(gh, gmaxp);
    gmax2_k<<<dim3(NGRAPH), dim3(512), 0, stream>>>(gmaxp, ge);
}